// Round 12
// baseline (14856.712 us; speedup 1.0000x reference)
//
#include <hip/hip_runtime.h>
#include <hip/hip_bf16.h>

// GRU: T=512, B=64, Cin=512, H=1024, 2 layers.
// Round 12: r11 (single-bf16 h/a streams, 64KB/CU/step, per-group barriers)
// + HARDENED barrier. r11's relaxed barrier raced under replay timing: data
// stores' L3-slice commit wasn't ordered before the counter increment at a
// different slice. Fix = r2's proven fence pair (release fence before the
// arrival add, acquire fence after spin exit, thread0 only). r2-vs-r3
// showed these fences cost ~0 in this kernel (no dirty L2: all our global
// stores are write-through; data loads are sc0sc1 and bypass L1/L2).

#define Hh   1024
#define Bz   64
#define Tt   512
#define Mrows (Tt*Bz)   // 32768
#define GBLK 64         // blocks per batch-group barrier

typedef __attribute__((ext_vector_type(8))) short short8;
typedef __attribute__((ext_vector_type(4))) float f32x4;
typedef __attribute__((ext_vector_type(4))) unsigned int u32x4;
typedef unsigned long long u64;

__device__ __forceinline__ unsigned short f2bf(float f){
  unsigned u = __builtin_bit_cast(unsigned, f);
  u += 0x7fffu + ((u >> 16) & 1u);          // round-to-nearest-even
  return (unsigned short)(u >> 16);
}
__device__ __forceinline__ float bf2f(unsigned short s){
  unsigned u = ((unsigned)s) << 16;
  return __builtin_bit_cast(float, u);
}

// write-through coherent stores (agent scope, relaxed)
__device__ __forceinline__ void cstore_u32(void* p, unsigned v){
  __hip_atomic_store((unsigned*)p, v, __ATOMIC_RELAXED, __HIP_MEMORY_SCOPE_AGENT);
}
__device__ __forceinline__ void cstore_u64(void* p, u64 v){
  __hip_atomic_store((u64*)p, v, __ATOMIC_RELAXED, __HIP_MEMORY_SCOPE_AGENT);
}

__device__ __forceinline__ void gload16(const void* g, void* l){
  __builtin_amdgcn_global_load_lds(
      (const __attribute__((address_space(1))) unsigned int*)g,
      (__attribute__((address_space(3))) unsigned int*)l, 16, 0, 0);
}

// GROUP barrier (64 arrivals): monotonic counter + r2's proven fence pair.
__device__ __forceinline__ void gbar(unsigned* ctr, unsigned* bk){
  __syncthreads();
  *bk += 1;
  if (threadIdx.x == 0){
    // release: order my block's data stores' commit before the arrival add
    __builtin_amdgcn_fence(__ATOMIC_RELEASE, "agent");
    __hip_atomic_fetch_add(ctr, 1u, __ATOMIC_RELAXED, __HIP_MEMORY_SCOPE_AGENT);
    const unsigned tgt = (*bk) * GBLK;
    while (__hip_atomic_load(ctr, __ATOMIC_RELAXED, __HIP_MEMORY_SCOPE_AGENT) < tgt)
      __builtin_amdgcn_s_sleep(1);
    // acquire: drop any stale cached lines before the next phase's reads
    __builtin_amdgcn_fence(__ATOMIC_ACQUIRE, "agent");
  }
  __syncthreads();
}

// ---- pipelined loads ----
#define CLOAD16(dst, base, kk) \
  asm volatile("global_load_dwordx4 %0, %1, off offset:%c2 sc0 sc1" \
               : "=v"(dst) : "v"(base), "i"((kk)*64));
#define PLOADF(dst, addr) \
  asm volatile("global_load_dword %0, %1, off" : "=v"(dst) : "v"(addr));
#define PLOADU16(dst, addr) \
  asm volatile("global_load_ushort %0, %1, off" : "=v"(dst) : "v"(addr));
#define VMWAIT(n) \
  asm volatile("s_waitcnt vmcnt(%c0)" :: "i"(n) : "memory"); \
  __builtin_amdgcn_sched_barrier(0);

// ---------------- prep kernels ----------------

__global__ __launch_bounds__(256) void k_cvt_bf16(const float* __restrict__ src,
                                                  unsigned short* __restrict__ dst, int n4){
  int i = blockIdx.x*blockDim.x + threadIdx.x;
  int stride = gridDim.x*blockDim.x;
  for (; i < n4; i += stride){
    float4 v = reinterpret_cast<const float4*>(src)[i];
    ushort4 o; o.x=f2bf(v.x); o.y=f2bf(v.y); o.z=f2bf(v.z); o.w=f2bf(v.w);
    reinterpret_cast<ushort4*>(dst)[i] = o;
  }
}

// fp32 (K,N) -> bf16 (N,K), 64x64 LDS tile
__global__ __launch_bounds__(256) void k_transpose_bf16(const float* __restrict__ src,
                                                        unsigned short* __restrict__ dst,
                                                        int K, int N){
  __shared__ float tile[64][65];
  int k0 = blockIdx.x * 64, n0 = blockIdx.y * 64;
  int t = threadIdx.x;
  int r = t >> 4, c4 = (t & 15) << 2;
  #pragma unroll
  for (int j = 0; j < 4; ++j){
    const float4 v = *reinterpret_cast<const float4*>(&src[(size_t)(k0 + r + j*16) * N + n0 + c4]);
    tile[r+j*16][c4+0]=v.x; tile[r+j*16][c4+1]=v.y;
    tile[r+j*16][c4+2]=v.z; tile[r+j*16][c4+3]=v.w;
  }
  __syncthreads();
  #pragma unroll
  for (int j = 0; j < 4; ++j){
    int nn = r + j*16;
    ushort4 o;
    o.x = f2bf(tile[c4+0][nn]); o.y = f2bf(tile[c4+1][nn]);
    o.z = f2bf(tile[c4+2][nn]); o.w = f2bf(tile[c4+3][nn]);
    *reinterpret_cast<ushort4*>(&dst[(size_t)(n0+nn)*K + k0 + c4]) = o;
  }
}

__global__ void k_bias_fold(const float* __restrict__ a, const float* __restrict__ b,
                            const float* __restrict__ c, const float* __restrict__ d,
                            float* __restrict__ out){
  int i = blockIdx.x*blockDim.x + threadIdx.x;
  if (i < 2048) out[i] = a[i] + b[i];
  else if (i < 3072) out[i] = c[i-2048] + d[i-2048];
}

// ---------------- big x-projection GEMM ----------------
__global__ __launch_bounds__(256) void k_xproj_gemm(
    const unsigned short* __restrict__ A, const unsigned short* __restrict__ Bt,
    const float* __restrict__ bias, unsigned short* __restrict__ outRZ,
    float* __restrict__ outC, int K)
{
  __shared__ __align__(16) unsigned short As[128*32];
  __shared__ __align__(16) unsigned short Bs[128*32];
  const int nb = blockIdx.x, mb = blockIdx.y;
  const int m0 = mb*128, n0 = nb*128;
  const int t = threadIdx.x, lane = t & 63, w = t >> 6;
  const int wr = w >> 1, wc = w & 1;
  const int lr = lane & 15, lq = lane >> 4;
  const int sr = t >> 2, scg = t & 3;
  f32x4 acc[4][4];
  const f32x4 zero4 = {0.f,0.f,0.f,0.f};
  #pragma unroll
  for (int mt=0;mt<4;++mt)
    #pragma unroll
    for (int nt=0;nt<4;++nt) acc[mt][nt] = zero4;

  const unsigned short* ga0 = &A [(size_t)(m0 + sr     )*K + scg*8];
  const unsigned short* ga1 = &A [(size_t)(m0 + sr + 64)*K + scg*8];
  const unsigned short* gb0 = &Bt[(size_t)(n0 + sr     )*K + scg*8];
  const unsigned short* gb1 = &Bt[(size_t)(n0 + sr + 64)*K + scg*8];
  char* lA = (char*)As + w*1024;
  char* lB = (char*)Bs + w*1024;
  const int kiters = K >> 5;
  for (int kt = 0; kt < kiters; ++kt){
    __syncthreads();
    gload16(ga0 + kt*32, lA);
    gload16(ga1 + kt*32, lA + 4096);
    gload16(gb0 + kt*32, lB);
    gload16(gb1 + kt*32, lB + 4096);
    asm volatile("s_waitcnt vmcnt(0)" ::: "memory");
    __syncthreads();
    short8 af[4], bfr[4];
    #pragma unroll
    for (int mt=0; mt<4; ++mt)
      af[mt] = *reinterpret_cast<const short8*>(&As[(wr*64 + mt*16 + lr)*32 + lq*8]);
    #pragma unroll
    for (int nt=0; nt<4; ++nt)
      bfr[nt] = *reinterpret_cast<const short8*>(&Bs[(wc*64 + nt*16 + lr)*32 + lq*8]);
    #pragma unroll
    for (int mt=0; mt<4; ++mt)
      #pragma unroll
      for (int nt=0; nt<4; ++nt)
        acc[mt][nt] = __builtin_amdgcn_mfma_f32_16x16x32_bf16(af[mt], bfr[nt], acc[mt][nt], 0,0,0);
  }
  const bool isRZ = (n0 < 2048);
  #pragma unroll
  for (int mt=0;mt<4;++mt){
    #pragma unroll
    for (int nt=0;nt<4;++nt){
      int gn = n0 + wc*64 + nt*16 + lr;
      float bv = bias[gn];
      #pragma unroll
      for (int i=0;i<4;++i){
        int gm = m0 + wr*64 + mt*16 + lq*4 + i;
        float v = acc[mt][nt][i] + bv;
        if (isRZ) outRZ[(size_t)gm*2048 + gn] = f2bf(v);
        else      outC [(size_t)gm*1024 + (gn - 2048)] = v;
      }
    }
  }
}

// ---------------- persistent per-layer recurrent kernel ----------------
// 256 blocks x 512 threads. Block (g,c): batch rows [16g,16g+16) x cols
// [16c,16c+16). Cross-block state: plain-bf16 h and a via sc0sc1 coherent
// ld/st. Per-group fenced 64-arrival barrier. 8 waves = K-slices of 128.
__global__ __launch_bounds__(512) void k_gru_layer(
    const unsigned short* __restrict__ Wrzg,   // (2048,1024) bf16
    const unsigned short* __restrict__ Whhg,   // (1024,1024) bf16
    const unsigned short* __restrict__ XprojRZ,// (T,64,2048) bf16, biases folded
    const float* __restrict__ XprojC,          // (T,64,1024) fp32, biases folded
    unsigned short* hhi, unsigned short* abhi,
    unsigned short* __restrict__ h0seq,        // L0: bf16 sequence out (else null)
    float* __restrict__ outseq,                // L1: fp32 sequence out (else null)
    float* __restrict__ hn,                    // final h slot
    unsigned* bar)                             // 4 counters, 256B apart
{
  __shared__ __align__(16) unsigned short WrzS[32*1024]; // 64KB rows0-15=r,16-31=z
  __shared__ __align__(16) unsigned short WhhS[16*1024]; // 32KB
  __shared__ float hloc[16][17];                         // block's fp32 h tile
  __shared__ float zloc[16][17];                         // block's z tile
  __shared__ float part[8][64][9];                       // 8-wave K-combine

  const int bid = blockIdx.x;
  const int g = bid & 3;          // batch group (rows 16g..16g+16)
  const int c = bid >> 2;         // column group (cols 16c..16c+16)
  const int tid = threadIdx.x;
  const int lane = tid & 63, w = tid >> 6;
  const int lr = lane & 15, lq = lane >> 4;
  unsigned* ctr = bar + g*64;     // this group's counter (own cacheline)
  unsigned bk = 0;

  // ---- stage weights into LDS (once), XOR-swizzled ----
  #pragma unroll
  for (int j = 0; j < 8; ++j){
    int lin = (tid + j*512) * 8;
    int n = lin >> 10, k = lin & 1023;
    int gr = (n < 16) ? (16*c + n) : (1024 + 16*c + (n - 16));
    short8 v = *reinterpret_cast<const short8*>(&Wrzg[(size_t)gr*1024 + k]);
    *reinterpret_cast<short8*>(&WrzS[(n*1024 + k) ^ ((n&7)<<3)]) = v;
  }
  #pragma unroll
  for (int j = 0; j < 4; ++j){
    int lin = (tid + j*512) * 8;
    int n = lin >> 10, k = lin & 1023;
    short8 v = *reinterpret_cast<const short8*>(&Whhg[(size_t)(16*c + n)*1024 + k]);
    *reinterpret_cast<short8*>(&WhhS[(n*1024 + k) ^ ((n&7)<<3)]) = v;
  }
  // ---- zero local h tile and global h slice (ws is poisoned) ----
  for (int idx = tid; idx < 16*17; idx += 512) ((float*)hloc)[idx] = 0.f;
  if (tid < 128){
    int r = tid >> 3, cp = (tid & 7) * 2;
    cstore_u32(&hhi[(16*g + r)*1024 + 16*c + cp], 0u);
  }
  gbar(ctr, &bk);

  const int kb = 128 * w;   // this wave's K-slice

  for (int t = 0; t < Tt; ++t){
    // ================= phase A: rz preact + gates =================
    {
      const unsigned short* xp = XprojRZ + (size_t)t*Bz*2048;
      // wave 0: r-col xproj scalars; wave 1: z-col (issued FIRST, retire first)
      unsigned xv[4];
      if (w == 0){
        #pragma unroll
        for (int i = 0; i < 4; ++i)
          PLOADU16(xv[i], &xp[(16*g + lq*4 + i)*2048 + 16*c + lr]);
      } else if (w == 1){
        #pragma unroll
        for (int i = 0; i < 4; ++i)
          PLOADU16(xv[i], &xp[(16*g + lq*4 + i)*2048 + 1024 + 16*c + lr]);
      }
      const unsigned short* hhp = hhi + (size_t)(16*g + lr)*1024 + kb + lq*8;
      u32x4 ahv[4];
      #pragma unroll
      for (int s = 0; s < 4; ++s){ CLOAD16(ahv[s], hhp, s) }
      f32x4 accr={0,0,0,0}, accz={0,0,0,0};
      #pragma unroll
      for (int k = 0; k < 4; ++k){
        VMWAIT(3 - k)
        short8 ah = __builtin_bit_cast(short8, ahv[k]);
        short8 br = *reinterpret_cast<const short8*>(
            &WrzS[(lr*1024 + kb + k*32 + lq*8) ^ ((lr&7)<<3)]);
        short8 bz = *reinterpret_cast<const short8*>(
            &WrzS[((16+lr)*1024 + kb + k*32 + lq*8) ^ ((lr&7)<<3)]);
        accr = __builtin_amdgcn_mfma_f32_16x16x32_bf16(ah, br, accr, 0,0,0);
        accz = __builtin_amdgcn_mfma_f32_16x16x32_bf16(ah, bz, accz, 0,0,0);
      }
      #pragma unroll
      for (int i = 0; i < 4; ++i){
        part[w][lane][i]   = accr[i];
        part[w][lane][4+i] = accz[i];
      }
      __syncthreads();
      if (w == 0){          // r-gate + a = h*r
        #pragma unroll
        for (int i = 0; i < 4; ++i){
          float s_ = 0.f;
          #pragma unroll
          for (int ww = 0; ww < 8; ++ww) s_ += part[ww][lane][i];
          int row = lq*4 + i;
          float pr = s_ + bf2f((unsigned short)xv[i]);
          float rg = 1.f / (1.f + __expf(-pr));
          float av = hloc[row][lr] * rg;
          unsigned short hi = f2bf(av);
          unsigned hi2 = (unsigned)__shfl_down((int)hi, 1) & 0xffffu;
          if (!(lane & 1))
            cstore_u32(&abhi[(16*g + row)*1024 + 16*c + lr], (unsigned)hi | (hi2<<16));
        }
      } else if (w == 1){   // z-gate
        #pragma unroll
        for (int i = 0; i < 4; ++i){
          float s_ = 0.f;
          #pragma unroll
          for (int ww = 0; ww < 8; ++ww) s_ += part[ww][lane][4+i];
          int row = lq*4 + i;
          float pz = s_ + bf2f((unsigned short)xv[i]);
          zloc[row][lr] = 1.f / (1.f + __expf(-pz));
        }
      }
    }
    gbar(ctr, &bk);
    // ================= phase B: cand + state update =================
    {
      const float* xc = XprojC + (size_t)t*Bz*1024;
      float xcv[4];
      if (w == 0){
        #pragma unroll
        for (int i = 0; i < 4; ++i)
          PLOADF(xcv[i], &xc[(16*g + lq*4 + i)*1024 + 16*c + lr]);
      }
      const unsigned short* ahp = abhi + (size_t)(16*g + lr)*1024 + kb + lq*8;
      u32x4 ahv[4];
      #pragma unroll
      for (int s = 0; s < 4; ++s){ CLOAD16(ahv[s], ahp, s) }
      f32x4 acc={0,0,0,0};
      #pragma unroll
      for (int k = 0; k < 4; ++k){
        VMWAIT(3 - k)
        short8 ah = __builtin_bit_cast(short8, ahv[k]);
        short8 bb = *reinterpret_cast<const short8*>(
            &WhhS[(lr*1024 + kb + k*32 + lq*8) ^ ((lr&7)<<3)]);
        acc = __builtin_amdgcn_mfma_f32_16x16x32_bf16(ah, bb, acc, 0,0,0);
      }
      #pragma unroll
      for (int i = 0; i < 4; ++i) part[w][lane][i] = acc[i];
      __syncthreads();
      if (w == 0){
        #pragma unroll
        for (int i = 0; i < 4; ++i){
          float s_ = 0.f;
          #pragma unroll
          for (int ww = 0; ww < 8; ++ww) s_ += part[ww][lane][i];
          int row = lq*4 + i;
          int grow = 16*g + row, gcol = 16*c + lr;
          float pre = s_ + xcv[i];
          float cand = tanhf(pre);
          float zg = zloc[row][lr];
          float h  = hloc[row][lr];
          float hnew = zg*h + (1.f - zg)*cand;
          hloc[row][lr] = hnew;
          unsigned short hi = f2bf(hnew);
          unsigned hi2 = (unsigned)__shfl_down((int)hi, 1) & 0xffffu;
          float hnew2 = __shfl_down(hnew, 1);
          if (!(lane & 1)){
            cstore_u32(&hhi[(size_t)grow*1024 + gcol], (unsigned)hi | (hi2<<16));
            if (h0seq)
              cstore_u32(&h0seq[(size_t)t*(Bz*Hh) + grow*1024 + gcol],
                         (unsigned)hi | (hi2<<16));
            if (outseq){
              float2 pr2 = {hnew, hnew2};
              cstore_u64(&outseq[(size_t)t*(Bz*Hh) + grow*1024 + gcol],
                         __builtin_bit_cast(u64, pr2));
            }
            if (t == Tt-1){
              float2 pr2 = {hnew, hnew2};
              cstore_u64(&hn[(size_t)grow*1024 + gcol], __builtin_bit_cast(u64, pr2));
            }
          }
        }
      }
    }
    gbar(ctr, &bk);
  }
}

// ---------------- host ----------------

extern "C" void kernel_launch(void* const* d_in, const int* in_sizes, int n_in,
                              void* d_out, int out_size, void* d_ws, size_t ws_size,
                              hipStream_t stream)
{
  (void)in_sizes; (void)n_in; (void)out_size; (void)ws_size;
  const float* X     = (const float*)d_in[0];
  const float* Wxrz0 = (const float*)d_in[1];
  const float* bxrz0 = (const float*)d_in[2];
  const float* Whrz0 = (const float*)d_in[3];
  const float* bhrz0 = (const float*)d_in[4];
  const float* Wxh0  = (const float*)d_in[5];
  const float* bxh0  = (const float*)d_in[6];
  const float* Whh0  = (const float*)d_in[7];
  const float* bhh0  = (const float*)d_in[8];
  const float* Wxrz1 = (const float*)d_in[9];
  const float* bxrz1 = (const float*)d_in[10];
  const float* Whrz1 = (const float*)d_in[11];
  const float* bhrz1 = (const float*)d_in[12];
  const float* Wxh1  = (const float*)d_in[13];
  const float* bxh1  = (const float*)d_in[14];
  const float* Whh1  = (const float*)d_in[15];
  const float* bhh1  = (const float*)d_in[16];

  char* p = (char*)d_ws;
  auto carve = [&](size_t bytes)->char*{
    char* r = p; p += (bytes + 255) & ~(size_t)255; return r;
  };
  unsigned short* Xbf    = (unsigned short*)carve((size_t)Mrows*512*2);
  unsigned short* W0t    = (unsigned short*)carve((size_t)3072*512*2);
  unsigned short* W1t    = (unsigned short*)carve((size_t)3072*1024*2);
  unsigned short* Whrz0t = (unsigned short*)carve((size_t)2048*1024*2);
  unsigned short* Whh0t  = (unsigned short*)carve((size_t)1024*1024*2);
  unsigned short* Whrz1t = (unsigned short*)carve((size_t)2048*1024*2);
  unsigned short* Whh1t  = (unsigned short*)carve((size_t)1024*1024*2);
  float* bias0 = (float*)carve(3072*4);
  float* bias1 = (float*)carve(3072*4);
  unsigned short* XprojRZ = (unsigned short*)carve((size_t)Mrows*2048*2);
  float*          XprojC  = (float*)carve((size_t)Mrows*1024*4);
  unsigned short* H0seq   = (unsigned short*)carve((size_t)Mrows*1024*2);
  unsigned short* hhi  = (unsigned short*)carve(Bz*Hh*2);
  unsigned short* abhi = (unsigned short*)carve(Bz*Hh*2);
  unsigned* bar = (unsigned*)carve(2048);   // L0: 4 counters @256B; L1: +1024B

  hipMemsetAsync(bar, 0, 2048, stream);

  k_cvt_bf16<<<2048,256,0,stream>>>(X, Xbf, Mrows*512/4);
  k_transpose_bf16<<<dim3(8,32), 256,0,stream>>>(Wxrz0, W0t, 512, 2048);
  k_transpose_bf16<<<dim3(8,16), 256,0,stream>>>(Wxh0,  W0t + (size_t)2048*512, 512, 1024);
  k_transpose_bf16<<<dim3(16,32),256,0,stream>>>(Whrz0, Whrz0t, 1024, 2048);
  k_transpose_bf16<<<dim3(16,16),256,0,stream>>>(Whh0,  Whh0t, 1024, 1024);
  k_transpose_bf16<<<dim3(16,32),256,0,stream>>>(Wxrz1, W1t, 1024, 2048);
  k_transpose_bf16<<<dim3(16,16),256,0,stream>>>(Wxh1,  W1t + (size_t)2048*1024, 1024, 1024);
  k_transpose_bf16<<<dim3(16,32),256,0,stream>>>(Whrz1, Whrz1t, 1024, 2048);
  k_transpose_bf16<<<dim3(16,16),256,0,stream>>>(Whh1,  Whh1t, 1024, 1024);
  k_bias_fold<<<12,256,0,stream>>>(bxrz0, bhrz0, bxh0, bhh0, bias0);
  k_bias_fold<<<12,256,0,stream>>>(bxrz1, bhrz1, bxh1, bhh1, bias1);

  float* out = (float*)d_out;
  float* hn0 = out + (size_t)Mrows*Hh;
  float* hn1 = hn0 + Bz*Hh;

  // ---- layer 0 ----
  k_xproj_gemm<<<dim3(24,256),256,0,stream>>>(Xbf, W0t, bias0, XprojRZ, XprojC, 512);
  k_gru_layer<<<256,512,0,stream>>>(Whrz0t, Whh0t, XprojRZ, XprojC,
                                    hhi, abhi,
                                    H0seq, nullptr, hn0, bar);
  // ---- layer 1 ----
  k_xproj_gemm<<<dim3(24,256),256,0,stream>>>(H0seq, W1t, bias1, XprojRZ, XprojC, 1024);
  k_gru_layer<<<256,512,0,stream>>>(Whrz1t, Whh1t, XprojRZ, XprojC,
                                    hhi, abhi,
                                    nullptr, out, hn1, bar + 256);
}

// Round 13
// 11225.235 us; speedup vs baseline: 1.3235x; 1.3235x over previous
//
#include <hip/hip_runtime.h>
#include <hip/hip_bf16.h>

// GRU: T=512, B=64, Cin=512, H=1024, 2 layers.
// Round 13: r12 minus the ACQUIRE fence. r12 proved the fenced barrier fixes
// r11's replay race (publish ordering), at +3.5us/phase for the fence PAIR.
// The acquire (buffer_inv: full L1+L2 invalidate) only protects CACHED
// consumers -- all our cross-block consumers are sc0sc1 loads that bypass
// L1/L2, so acquire is pure overhead. Keep only the RELEASE fence
// (s_waitcnt + buffer_wbl2) in thread0 before the arrival add: that is the
// minimal AMD agent-release publish. Everything else identical to r12.

#define Hh   1024
#define Bz   64
#define Tt   512
#define Mrows (Tt*Bz)   // 32768
#define GBLK 64         // blocks per batch-group barrier

typedef __attribute__((ext_vector_type(8))) short short8;
typedef __attribute__((ext_vector_type(4))) float f32x4;
typedef __attribute__((ext_vector_type(4))) unsigned int u32x4;
typedef unsigned long long u64;

__device__ __forceinline__ unsigned short f2bf(float f){
  unsigned u = __builtin_bit_cast(unsigned, f);
  u += 0x7fffu + ((u >> 16) & 1u);          // round-to-nearest-even
  return (unsigned short)(u >> 16);
}
__device__ __forceinline__ float bf2f(unsigned short s){
  unsigned u = ((unsigned)s) << 16;
  return __builtin_bit_cast(float, u);
}

// write-through coherent stores (agent scope, relaxed)
__device__ __forceinline__ void cstore_u32(void* p, unsigned v){
  __hip_atomic_store((unsigned*)p, v, __ATOMIC_RELAXED, __HIP_MEMORY_SCOPE_AGENT);
}
__device__ __forceinline__ void cstore_u64(void* p, u64 v){
  __hip_atomic_store((u64*)p, v, __ATOMIC_RELAXED, __HIP_MEMORY_SCOPE_AGENT);
}

__device__ __forceinline__ void gload16(const void* g, void* l){
  __builtin_amdgcn_global_load_lds(
      (const __attribute__((address_space(1))) unsigned int*)g,
      (__attribute__((address_space(3))) unsigned int*)l, 16, 0, 0);
}

// GROUP barrier (64 arrivals): monotonic counter + RELEASE-only publish.
__device__ __forceinline__ void gbar(unsigned* ctr, unsigned* bk){
  __syncthreads();
  *bk += 1;
  if (threadIdx.x == 0){
    // release: publish my block's data stores before the arrival add
    __builtin_amdgcn_fence(__ATOMIC_RELEASE, "agent");
    __hip_atomic_fetch_add(ctr, 1u, __ATOMIC_RELAXED, __HIP_MEMORY_SCOPE_AGENT);
    const unsigned tgt = (*bk) * GBLK;
    while (__hip_atomic_load(ctr, __ATOMIC_RELAXED, __HIP_MEMORY_SCOPE_AGENT) < tgt)
      __builtin_amdgcn_s_sleep(1);
    // no acquire: all cross-block consumer loads are sc0sc1 (L1/L2-bypass)
  }
  __syncthreads();
}

// ---- pipelined loads ----
#define CLOAD16(dst, base, kk) \
  asm volatile("global_load_dwordx4 %0, %1, off offset:%c2 sc0 sc1" \
               : "=v"(dst) : "v"(base), "i"((kk)*64));
#define PLOADF(dst, addr) \
  asm volatile("global_load_dword %0, %1, off" : "=v"(dst) : "v"(addr));
#define PLOADU16(dst, addr) \
  asm volatile("global_load_ushort %0, %1, off" : "=v"(dst) : "v"(addr));
#define VMWAIT(n) \
  asm volatile("s_waitcnt vmcnt(%c0)" :: "i"(n) : "memory"); \
  __builtin_amdgcn_sched_barrier(0);

// ---------------- prep kernels ----------------

__global__ __launch_bounds__(256) void k_cvt_bf16(const float* __restrict__ src,
                                                  unsigned short* __restrict__ dst, int n4){
  int i = blockIdx.x*blockDim.x + threadIdx.x;
  int stride = gridDim.x*blockDim.x;
  for (; i < n4; i += stride){
    float4 v = reinterpret_cast<const float4*>(src)[i];
    ushort4 o; o.x=f2bf(v.x); o.y=f2bf(v.y); o.z=f2bf(v.z); o.w=f2bf(v.w);
    reinterpret_cast<ushort4*>(dst)[i] = o;
  }
}

// fp32 (K,N) -> bf16 (N,K), 64x64 LDS tile
__global__ __launch_bounds__(256) void k_transpose_bf16(const float* __restrict__ src,
                                                        unsigned short* __restrict__ dst,
                                                        int K, int N){
  __shared__ float tile[64][65];
  int k0 = blockIdx.x * 64, n0 = blockIdx.y * 64;
  int t = threadIdx.x;
  int r = t >> 4, c4 = (t & 15) << 2;
  #pragma unroll
  for (int j = 0; j < 4; ++j){
    const float4 v = *reinterpret_cast<const float4*>(&src[(size_t)(k0 + r + j*16) * N + n0 + c4]);
    tile[r+j*16][c4+0]=v.x; tile[r+j*16][c4+1]=v.y;
    tile[r+j*16][c4+2]=v.z; tile[r+j*16][c4+3]=v.w;
  }
  __syncthreads();
  #pragma unroll
  for (int j = 0; j < 4; ++j){
    int nn = r + j*16;
    ushort4 o;
    o.x = f2bf(tile[c4+0][nn]); o.y = f2bf(tile[c4+1][nn]);
    o.z = f2bf(tile[c4+2][nn]); o.w = f2bf(tile[c4+3][nn]);
    *reinterpret_cast<ushort4*>(&dst[(size_t)(n0+nn)*K + k0 + c4]) = o;
  }
}

__global__ void k_bias_fold(const float* __restrict__ a, const float* __restrict__ b,
                            const float* __restrict__ c, const float* __restrict__ d,
                            float* __restrict__ out){
  int i = blockIdx.x*blockDim.x + threadIdx.x;
  if (i < 2048) out[i] = a[i] + b[i];
  else if (i < 3072) out[i] = c[i-2048] + d[i-2048];
}

// ---------------- big x-projection GEMM ----------------
__global__ __launch_bounds__(256) void k_xproj_gemm(
    const unsigned short* __restrict__ A, const unsigned short* __restrict__ Bt,
    const float* __restrict__ bias, unsigned short* __restrict__ outRZ,
    float* __restrict__ outC, int K)
{
  __shared__ __align__(16) unsigned short As[128*32];
  __shared__ __align__(16) unsigned short Bs[128*32];
  const int nb = blockIdx.x, mb = blockIdx.y;
  const int m0 = mb*128, n0 = nb*128;
  const int t = threadIdx.x, lane = t & 63, w = t >> 6;
  const int wr = w >> 1, wc = w & 1;
  const int lr = lane & 15, lq = lane >> 4;
  const int sr = t >> 2, scg = t & 3;
  f32x4 acc[4][4];
  const f32x4 zero4 = {0.f,0.f,0.f,0.f};
  #pragma unroll
  for (int mt=0;mt<4;++mt)
    #pragma unroll
    for (int nt=0;nt<4;++nt) acc[mt][nt] = zero4;

  const unsigned short* ga0 = &A [(size_t)(m0 + sr     )*K + scg*8];
  const unsigned short* ga1 = &A [(size_t)(m0 + sr + 64)*K + scg*8];
  const unsigned short* gb0 = &Bt[(size_t)(n0 + sr     )*K + scg*8];
  const unsigned short* gb1 = &Bt[(size_t)(n0 + sr + 64)*K + scg*8];
  char* lA = (char*)As + w*1024;
  char* lB = (char*)Bs + w*1024;
  const int kiters = K >> 5;
  for (int kt = 0; kt < kiters; ++kt){
    __syncthreads();
    gload16(ga0 + kt*32, lA);
    gload16(ga1 + kt*32, lA + 4096);
    gload16(gb0 + kt*32, lB);
    gload16(gb1 + kt*32, lB + 4096);
    asm volatile("s_waitcnt vmcnt(0)" ::: "memory");
    __syncthreads();
    short8 af[4], bfr[4];
    #pragma unroll
    for (int mt=0; mt<4; ++mt)
      af[mt] = *reinterpret_cast<const short8*>(&As[(wr*64 + mt*16 + lr)*32 + lq*8]);
    #pragma unroll
    for (int nt=0; nt<4; ++nt)
      bfr[nt] = *reinterpret_cast<const short8*>(&Bs[(wc*64 + nt*16 + lr)*32 + lq*8]);
    #pragma unroll
    for (int mt=0; mt<4; ++mt)
      #pragma unroll
      for (int nt=0; nt<4; ++nt)
        acc[mt][nt] = __builtin_amdgcn_mfma_f32_16x16x32_bf16(af[mt], bfr[nt], acc[mt][nt], 0,0,0);
  }
  const bool isRZ = (n0 < 2048);
  #pragma unroll
  for (int mt=0;mt<4;++mt){
    #pragma unroll
    for (int nt=0;nt<4;++nt){
      int gn = n0 + wc*64 + nt*16 + lr;
      float bv = bias[gn];
      #pragma unroll
      for (int i=0;i<4;++i){
        int gm = m0 + wr*64 + mt*16 + lq*4 + i;
        float v = acc[mt][nt][i] + bv;
        if (isRZ) outRZ[(size_t)gm*2048 + gn] = f2bf(v);
        else      outC [(size_t)gm*1024 + (gn - 2048)] = v;
      }
    }
  }
}

// ---------------- persistent per-layer recurrent kernel ----------------
// 256 blocks x 512 threads. Block (g,c): batch rows [16g,16g+16) x cols
// [16c,16c+16). Cross-block state: plain-bf16 h and a via sc0sc1 coherent
// ld/st. Per-group release-fenced 64-arrival barrier. 8 waves = K-slices.
__global__ __launch_bounds__(512) void k_gru_layer(
    const unsigned short* __restrict__ Wrzg,   // (2048,1024) bf16
    const unsigned short* __restrict__ Whhg,   // (1024,1024) bf16
    const unsigned short* __restrict__ XprojRZ,// (T,64,2048) bf16, biases folded
    const float* __restrict__ XprojC,          // (T,64,1024) fp32, biases folded
    unsigned short* hhi, unsigned short* abhi,
    unsigned short* __restrict__ h0seq,        // L0: bf16 sequence out (else null)
    float* __restrict__ outseq,                // L1: fp32 sequence out (else null)
    float* __restrict__ hn,                    // final h slot
    unsigned* bar)                             // 4 counters, 256B apart
{
  __shared__ __align__(16) unsigned short WrzS[32*1024]; // 64KB rows0-15=r,16-31=z
  __shared__ __align__(16) unsigned short WhhS[16*1024]; // 32KB
  __shared__ float hloc[16][17];                         // block's fp32 h tile
  __shared__ float zloc[16][17];                         // block's z tile
  __shared__ float part[8][64][9];                       // 8-wave K-combine

  const int bid = blockIdx.x;
  const int g = bid & 3;          // batch group (rows 16g..16g+16)
  const int c = bid >> 2;         // column group (cols 16c..16c+16)
  const int tid = threadIdx.x;
  const int lane = tid & 63, w = tid >> 6;
  const int lr = lane & 15, lq = lane >> 4;
  unsigned* ctr = bar + g*64;     // this group's counter (own cacheline)
  unsigned bk = 0;

  // ---- stage weights into LDS (once), XOR-swizzled ----
  #pragma unroll
  for (int j = 0; j < 8; ++j){
    int lin = (tid + j*512) * 8;
    int n = lin >> 10, k = lin & 1023;
    int gr = (n < 16) ? (16*c + n) : (1024 + 16*c + (n - 16));
    short8 v = *reinterpret_cast<const short8*>(&Wrzg[(size_t)gr*1024 + k]);
    *reinterpret_cast<short8*>(&WrzS[(n*1024 + k) ^ ((n&7)<<3)]) = v;
  }
  #pragma unroll
  for (int j = 0; j < 4; ++j){
    int lin = (tid + j*512) * 8;
    int n = lin >> 10, k = lin & 1023;
    short8 v = *reinterpret_cast<const short8*>(&Whhg[(size_t)(16*c + n)*1024 + k]);
    *reinterpret_cast<short8*>(&WhhS[(n*1024 + k) ^ ((n&7)<<3)]) = v;
  }
  // ---- zero local h tile and global h slice (ws is poisoned) ----
  for (int idx = tid; idx < 16*17; idx += 512) ((float*)hloc)[idx] = 0.f;
  if (tid < 128){
    int r = tid >> 3, cp = (tid & 7) * 2;
    cstore_u32(&hhi[(16*g + r)*1024 + 16*c + cp], 0u);
  }
  gbar(ctr, &bk);

  const int kb = 128 * w;   // this wave's K-slice

  for (int t = 0; t < Tt; ++t){
    // ================= phase A: rz preact + gates =================
    {
      const unsigned short* xp = XprojRZ + (size_t)t*Bz*2048;
      // wave 0: r-col xproj scalars; wave 1: z-col (issued FIRST, retire first)
      unsigned xv[4];
      if (w == 0){
        #pragma unroll
        for (int i = 0; i < 4; ++i)
          PLOADU16(xv[i], &xp[(16*g + lq*4 + i)*2048 + 16*c + lr]);
      } else if (w == 1){
        #pragma unroll
        for (int i = 0; i < 4; ++i)
          PLOADU16(xv[i], &xp[(16*g + lq*4 + i)*2048 + 1024 + 16*c + lr]);
      }
      const unsigned short* hhp = hhi + (size_t)(16*g + lr)*1024 + kb + lq*8;
      u32x4 ahv[4];
      #pragma unroll
      for (int s = 0; s < 4; ++s){ CLOAD16(ahv[s], hhp, s) }
      f32x4 accr={0,0,0,0}, accz={0,0,0,0};
      #pragma unroll
      for (int k = 0; k < 4; ++k){
        VMWAIT(3 - k)
        short8 ah = __builtin_bit_cast(short8, ahv[k]);
        short8 br = *reinterpret_cast<const short8*>(
            &WrzS[(lr*1024 + kb + k*32 + lq*8) ^ ((lr&7)<<3)]);
        short8 bz = *reinterpret_cast<const short8*>(
            &WrzS[((16+lr)*1024 + kb + k*32 + lq*8) ^ ((lr&7)<<3)]);
        accr = __builtin_amdgcn_mfma_f32_16x16x32_bf16(ah, br, accr, 0,0,0);
        accz = __builtin_amdgcn_mfma_f32_16x16x32_bf16(ah, bz, accz, 0,0,0);
      }
      #pragma unroll
      for (int i = 0; i < 4; ++i){
        part[w][lane][i]   = accr[i];
        part[w][lane][4+i] = accz[i];
      }
      __syncthreads();
      if (w == 0){          // r-gate + a = h*r
        #pragma unroll
        for (int i = 0; i < 4; ++i){
          float s_ = 0.f;
          #pragma unroll
          for (int ww = 0; ww < 8; ++ww) s_ += part[ww][lane][i];
          int row = lq*4 + i;
          float pr = s_ + bf2f((unsigned short)xv[i]);
          float rg = 1.f / (1.f + __expf(-pr));
          float av = hloc[row][lr] * rg;
          unsigned short hi = f2bf(av);
          unsigned hi2 = (unsigned)__shfl_down((int)hi, 1) & 0xffffu;
          if (!(lane & 1))
            cstore_u32(&abhi[(16*g + row)*1024 + 16*c + lr], (unsigned)hi | (hi2<<16));
        }
      } else if (w == 1){   // z-gate
        #pragma unroll
        for (int i = 0; i < 4; ++i){
          float s_ = 0.f;
          #pragma unroll
          for (int ww = 0; ww < 8; ++ww) s_ += part[ww][lane][4+i];
          int row = lq*4 + i;
          float pz = s_ + bf2f((unsigned short)xv[i]);
          zloc[row][lr] = 1.f / (1.f + __expf(-pz));
        }
      }
    }
    gbar(ctr, &bk);
    // ================= phase B: cand + state update =================
    {
      const float* xc = XprojC + (size_t)t*Bz*1024;
      float xcv[4];
      if (w == 0){
        #pragma unroll
        for (int i = 0; i < 4; ++i)
          PLOADF(xcv[i], &xc[(16*g + lq*4 + i)*1024 + 16*c + lr]);
      }
      const unsigned short* ahp = abhi + (size_t)(16*g + lr)*1024 + kb + lq*8;
      u32x4 ahv[4];
      #pragma unroll
      for (int s = 0; s < 4; ++s){ CLOAD16(ahv[s], ahp, s) }
      f32x4 acc={0,0,0,0};
      #pragma unroll
      for (int k = 0; k < 4; ++k){
        VMWAIT(3 - k)
        short8 ah = __builtin_bit_cast(short8, ahv[k]);
        short8 bb = *reinterpret_cast<const short8*>(
            &WhhS[(lr*1024 + kb + k*32 + lq*8) ^ ((lr&7)<<3)]);
        acc = __builtin_amdgcn_mfma_f32_16x16x32_bf16(ah, bb, acc, 0,0,0);
      }
      #pragma unroll
      for (int i = 0; i < 4; ++i) part[w][lane][i] = acc[i];
      __syncthreads();
      if (w == 0){
        #pragma unroll
        for (int i = 0; i < 4; ++i){
          float s_ = 0.f;
          #pragma unroll
          for (int ww = 0; ww < 8; ++ww) s_ += part[ww][lane][i];
          int row = lq*4 + i;
          int grow = 16*g + row, gcol = 16*c + lr;
          float pre = s_ + xcv[i];
          float cand = tanhf(pre);
          float zg = zloc[row][lr];
          float h  = hloc[row][lr];
          float hnew = zg*h + (1.f - zg)*cand;
          hloc[row][lr] = hnew;
          unsigned short hi = f2bf(hnew);
          unsigned hi2 = (unsigned)__shfl_down((int)hi, 1) & 0xffffu;
          float hnew2 = __shfl_down(hnew, 1);
          if (!(lane & 1)){
            cstore_u32(&hhi[(size_t)grow*1024 + gcol], (unsigned)hi | (hi2<<16));
            if (h0seq)
              cstore_u32(&h0seq[(size_t)t*(Bz*Hh) + grow*1024 + gcol],
                         (unsigned)hi | (hi2<<16));
            if (outseq){
              float2 pr2 = {hnew, hnew2};
              cstore_u64(&outseq[(size_t)t*(Bz*Hh) + grow*1024 + gcol],
                         __builtin_bit_cast(u64, pr2));
            }
            if (t == Tt-1){
              float2 pr2 = {hnew, hnew2};
              cstore_u64(&hn[(size_t)grow*1024 + gcol], __builtin_bit_cast(u64, pr2));
            }
          }
        }
      }
    }
    gbar(ctr, &bk);
  }
}

// ---------------- host ----------------

extern "C" void kernel_launch(void* const* d_in, const int* in_sizes, int n_in,
                              void* d_out, int out_size, void* d_ws, size_t ws_size,
                              hipStream_t stream)
{
  (void)in_sizes; (void)n_in; (void)out_size; (void)ws_size;
  const float* X     = (const float*)d_in[0];
  const float* Wxrz0 = (const float*)d_in[1];
  const float* bxrz0 = (const float*)d_in[2];
  const float* Whrz0 = (const float*)d_in[3];
  const float* bhrz0 = (const float*)d_in[4];
  const float* Wxh0  = (const float*)d_in[5];
  const float* bxh0  = (const float*)d_in[6];
  const float* Whh0  = (const float*)d_in[7];
  const float* bhh0  = (const float*)d_in[8];
  const float* Wxrz1 = (const float*)d_in[9];
  const float* bxrz1 = (const float*)d_in[10];
  const float* Whrz1 = (const float*)d_in[11];
  const float* bhrz1 = (const float*)d_in[12];
  const float* Wxh1  = (const float*)d_in[13];
  const float* bxh1  = (const float*)d_in[14];
  const float* Whh1  = (const float*)d_in[15];
  const float* bhh1  = (const float*)d_in[16];

  char* p = (char*)d_ws;
  auto carve = [&](size_t bytes)->char*{
    char* r = p; p += (bytes + 255) & ~(size_t)255; return r;
  };
  unsigned short* Xbf    = (unsigned short*)carve((size_t)Mrows*512*2);
  unsigned short* W0t    = (unsigned short*)carve((size_t)3072*512*2);
  unsigned short* W1t    = (unsigned short*)carve((size_t)3072*1024*2);
  unsigned short* Whrz0t = (unsigned short*)carve((size_t)2048*1024*2);
  unsigned short* Whh0t  = (unsigned short*)carve((size_t)1024*1024*2);
  unsigned short* Whrz1t = (unsigned short*)carve((size_t)2048*1024*2);
  unsigned short* Whh1t  = (unsigned short*)carve((size_t)1024*1024*2);
  float* bias0 = (float*)carve(3072*4);
  float* bias1 = (float*)carve(3072*4);
  unsigned short* XprojRZ = (unsigned short*)carve((size_t)Mrows*2048*2);
  float*          XprojC  = (float*)carve((size_t)Mrows*1024*4);
  unsigned short* H0seq   = (unsigned short*)carve((size_t)Mrows*1024*2);
  unsigned short* hhi  = (unsigned short*)carve(Bz*Hh*2);
  unsigned short* abhi = (unsigned short*)carve(Bz*Hh*2);
  unsigned* bar = (unsigned*)carve(2048);   // L0: 4 counters @256B; L1: +1024B

  hipMemsetAsync(bar, 0, 2048, stream);

  k_cvt_bf16<<<2048,256,0,stream>>>(X, Xbf, Mrows*512/4);
  k_transpose_bf16<<<dim3(8,32), 256,0,stream>>>(Wxrz0, W0t, 512, 2048);
  k_transpose_bf16<<<dim3(8,16), 256,0,stream>>>(Wxh0,  W0t + (size_t)2048*512, 512, 1024);
  k_transpose_bf16<<<dim3(16,32),256,0,stream>>>(Whrz0, Whrz0t, 1024, 2048);
  k_transpose_bf16<<<dim3(16,16),256,0,stream>>>(Whh0,  Whh0t, 1024, 1024);
  k_transpose_bf16<<<dim3(16,32),256,0,stream>>>(Wxrz1, W1t, 1024, 2048);
  k_transpose_bf16<<<dim3(16,16),256,0,stream>>>(Wxh1,  W1t + (size_t)2048*1024, 1024, 1024);
  k_transpose_bf16<<<dim3(16,32),256,0,stream>>>(Whrz1, Whrz1t, 1024, 2048);
  k_transpose_bf16<<<dim3(16,16),256,0,stream>>>(Whh1,  Whh1t, 1024, 1024);
  k_bias_fold<<<12,256,0,stream>>>(bxrz0, bhrz0, bxh0, bhh0, bias0);
  k_bias_fold<<<12,256,0,stream>>>(bxrz1, bhrz1, bxh1, bhh1, bias1);

  float* out = (float*)d_out;
  float* hn0 = out + (size_t)Mrows*Hh;
  float* hn1 = hn0 + Bz*Hh;

  // ---- layer 0 ----
  k_xproj_gemm<<<dim3(24,256),256,0,stream>>>(Xbf, W0t, bias0, XprojRZ, XprojC, 512);
  k_gru_layer<<<256,512,0,stream>>>(Whrz0t, Whh0t, XprojRZ, XprojC,
                                    hhi, abhi,
                                    H0seq, nullptr, hn0, bar);
  // ---- layer 1 ----
  k_xproj_gemm<<<dim3(24,256),256,0,stream>>>(H0seq, W1t, bias1, XprojRZ, XprojC, 1024);
  k_gru_layer<<<256,512,0,stream>>>(Whrz1t, Whh1t, XprojRZ, XprojC,
                                    hhi, abhi,
                                    nullptr, out, hn1, bar + 256);
}

// Round 14
// 7877.555 us; speedup vs baseline: 1.8860x; 1.4250x over previous
//
#include <hip/hip_runtime.h>
#include <hip/hip_bf16.h>

// GRU: T=512, B=64, Cin=512, H=1024, 2 layers.
// Round 14: r13 + HIERARCHICAL publish. r13's release fence (buffer_wbl2) ran
// in all 256 blocks (~2us/phase, 32 concurrent L2-walks per XCD serialize).
// One wbl2 per XCD covers ALL resident blocks' L2->L3 writes, so: dynamic
// census by runtime XCC_ID (mapping-agnostic) -> per-XCD arrival counter ->
// census-slot-0 claimant waits its XCD's count, does the ONE release fence,
// arrives at the group counter; readers spin on group count == nXCDs.
// Data path and numerics byte-identical to r13 (absmax 8.5e-3).

#define Hh   1024
#define Bz   64
#define Tt   512
#define Mrows (Tt*Bz)   // 32768
#define GBLK 64         // blocks per batch-group

typedef __attribute__((ext_vector_type(8))) short short8;
typedef __attribute__((ext_vector_type(4))) float f32x4;
typedef __attribute__((ext_vector_type(4))) unsigned int u32x4;
typedef unsigned long long u64;

__device__ __forceinline__ unsigned short f2bf(float f){
  unsigned u = __builtin_bit_cast(unsigned, f);
  u += 0x7fffu + ((u >> 16) & 1u);          // round-to-nearest-even
  return (unsigned short)(u >> 16);
}
__device__ __forceinline__ float bf2f(unsigned short s){
  unsigned u = ((unsigned)s) << 16;
  return __builtin_bit_cast(float, u);
}

// write-through coherent stores (agent scope, relaxed)
__device__ __forceinline__ void cstore_u32(void* p, unsigned v){
  __hip_atomic_store((unsigned*)p, v, __ATOMIC_RELAXED, __HIP_MEMORY_SCOPE_AGENT);
}
__device__ __forceinline__ void cstore_u64(void* p, u64 v){
  __hip_atomic_store((u64*)p, v, __ATOMIC_RELAXED, __HIP_MEMORY_SCOPE_AGENT);
}
__device__ __forceinline__ unsigned cld(unsigned* p){
  return __hip_atomic_load(p, __ATOMIC_RELAXED, __HIP_MEMORY_SCOPE_AGENT);
}
__device__ __forceinline__ unsigned cadd(unsigned* p){
  return __hip_atomic_fetch_add(p, 1u, __ATOMIC_RELAXED, __HIP_MEMORY_SCOPE_AGENT);
}

__device__ __forceinline__ void gload16(const void* g, void* l){
  __builtin_amdgcn_global_load_lds(
      (const __attribute__((address_space(1))) unsigned int*)g,
      (__attribute__((address_space(3))) unsigned int*)l, 16, 0, 0);
}

// ---- pipelined loads ----
#define CLOAD16(dst, base, kk) \
  asm volatile("global_load_dwordx4 %0, %1, off offset:%c2 sc0 sc1" \
               : "=v"(dst) : "v"(base), "i"((kk)*64));
#define PLOADF(dst, addr) \
  asm volatile("global_load_dword %0, %1, off" : "=v"(dst) : "v"(addr));
#define PLOADU16(dst, addr) \
  asm volatile("global_load_ushort %0, %1, off" : "=v"(dst) : "v"(addr));
#define VMWAIT(n) \
  asm volatile("s_waitcnt vmcnt(%c0)" :: "i"(n) : "memory"); \
  __builtin_amdgcn_sched_barrier(0);

// ---------------- prep kernels ----------------

__global__ __launch_bounds__(256) void k_cvt_bf16(const float* __restrict__ src,
                                                  unsigned short* __restrict__ dst, int n4){
  int i = blockIdx.x*blockDim.x + threadIdx.x;
  int stride = gridDim.x*blockDim.x;
  for (; i < n4; i += stride){
    float4 v = reinterpret_cast<const float4*>(src)[i];
    ushort4 o; o.x=f2bf(v.x); o.y=f2bf(v.y); o.z=f2bf(v.z); o.w=f2bf(v.w);
    reinterpret_cast<ushort4*>(dst)[i] = o;
  }
}

// fp32 (K,N) -> bf16 (N,K), 64x64 LDS tile
__global__ __launch_bounds__(256) void k_transpose_bf16(const float* __restrict__ src,
                                                        unsigned short* __restrict__ dst,
                                                        int K, int N){
  __shared__ float tile[64][65];
  int k0 = blockIdx.x * 64, n0 = blockIdx.y * 64;
  int t = threadIdx.x;
  int r = t >> 4, c4 = (t & 15) << 2;
  #pragma unroll
  for (int j = 0; j < 4; ++j){
    const float4 v = *reinterpret_cast<const float4*>(&src[(size_t)(k0 + r + j*16) * N + n0 + c4]);
    tile[r+j*16][c4+0]=v.x; tile[r+j*16][c4+1]=v.y;
    tile[r+j*16][c4+2]=v.z; tile[r+j*16][c4+3]=v.w;
  }
  __syncthreads();
  #pragma unroll
  for (int j = 0; j < 4; ++j){
    int nn = r + j*16;
    ushort4 o;
    o.x = f2bf(tile[c4+0][nn]); o.y = f2bf(tile[c4+1][nn]);
    o.z = f2bf(tile[c4+2][nn]); o.w = f2bf(tile[c4+3][nn]);
    *reinterpret_cast<ushort4*>(&dst[(size_t)(n0+nn)*K + k0 + c4]) = o;
  }
}

__global__ void k_bias_fold(const float* __restrict__ a, const float* __restrict__ b,
                            const float* __restrict__ c, const float* __restrict__ d,
                            float* __restrict__ out){
  int i = blockIdx.x*blockDim.x + threadIdx.x;
  if (i < 2048) out[i] = a[i] + b[i];
  else if (i < 3072) out[i] = c[i-2048] + d[i-2048];
}

// ---------------- big x-projection GEMM ----------------
__global__ __launch_bounds__(256) void k_xproj_gemm(
    const unsigned short* __restrict__ A, const unsigned short* __restrict__ Bt,
    const float* __restrict__ bias, unsigned short* __restrict__ outRZ,
    float* __restrict__ outC, int K)
{
  __shared__ __align__(16) unsigned short As[128*32];
  __shared__ __align__(16) unsigned short Bs[128*32];
  const int nb = blockIdx.x, mb = blockIdx.y;
  const int m0 = mb*128, n0 = nb*128;
  const int t = threadIdx.x, lane = t & 63, w = t >> 6;
  const int wr = w >> 1, wc = w & 1;
  const int lr = lane & 15, lq = lane >> 4;
  const int sr = t >> 2, scg = t & 3;
  f32x4 acc[4][4];
  const f32x4 zero4 = {0.f,0.f,0.f,0.f};
  #pragma unroll
  for (int mt=0;mt<4;++mt)
    #pragma unroll
    for (int nt=0;nt<4;++nt) acc[mt][nt] = zero4;

  const unsigned short* ga0 = &A [(size_t)(m0 + sr     )*K + scg*8];
  const unsigned short* ga1 = &A [(size_t)(m0 + sr + 64)*K + scg*8];
  const unsigned short* gb0 = &Bt[(size_t)(n0 + sr     )*K + scg*8];
  const unsigned short* gb1 = &Bt[(size_t)(n0 + sr + 64)*K + scg*8];
  char* lA = (char*)As + w*1024;
  char* lB = (char*)Bs + w*1024;
  const int kiters = K >> 5;
  for (int kt = 0; kt < kiters; ++kt){
    __syncthreads();
    gload16(ga0 + kt*32, lA);
    gload16(ga1 + kt*32, lA + 4096);
    gload16(gb0 + kt*32, lB);
    gload16(gb1 + kt*32, lB + 4096);
    asm volatile("s_waitcnt vmcnt(0)" ::: "memory");
    __syncthreads();
    short8 af[4], bfr[4];
    #pragma unroll
    for (int mt=0; mt<4; ++mt)
      af[mt] = *reinterpret_cast<const short8*>(&As[(wr*64 + mt*16 + lr)*32 + lq*8]);
    #pragma unroll
    for (int nt=0; nt<4; ++nt)
      bfr[nt] = *reinterpret_cast<const short8*>(&Bs[(wc*64 + nt*16 + lr)*32 + lq*8]);
    #pragma unroll
    for (int mt=0; mt<4; ++mt)
      #pragma unroll
      for (int nt=0; nt<4; ++nt)
        acc[mt][nt] = __builtin_amdgcn_mfma_f32_16x16x32_bf16(af[mt], bfr[nt], acc[mt][nt], 0,0,0);
  }
  const bool isRZ = (n0 < 2048);
  #pragma unroll
  for (int mt=0;mt<4;++mt){
    #pragma unroll
    for (int nt=0;nt<4;++nt){
      int gn = n0 + wc*64 + nt*16 + lr;
      float bv = bias[gn];
      #pragma unroll
      for (int i=0;i<4;++i){
        int gm = m0 + wr*64 + mt*16 + lq*4 + i;
        float v = acc[mt][nt][i] + bv;
        if (isRZ) outRZ[(size_t)gm*2048 + gn] = f2bf(v);
        else      outC [(size_t)gm*1024 + (gn - 2048)] = v;
      }
    }
  }
}

// ---------------- persistent per-layer recurrent kernel ----------------
// 256 blocks x 512 threads. Block (g,c): batch rows [16g,16g+16) x cols
// [16c,16c+16). Cross-block state: plain-bf16 h and a via sc0sc1 ld/st.
// Hierarchical publish: per-XCD arrival + one claimant fence per XCD.
// bar layout (u32, per layer): c2[g] @ g*32; c1[g][x] @ 128+(g*8+x)*32;
// census[g][x] @ 1152+g*8+x.
__global__ __launch_bounds__(512) void k_gru_layer(
    const unsigned short* __restrict__ Wrzg,   // (2048,1024) bf16
    const unsigned short* __restrict__ Whhg,   // (1024,1024) bf16
    const unsigned short* __restrict__ XprojRZ,// (T,64,2048) bf16, biases folded
    const float* __restrict__ XprojC,          // (T,64,1024) fp32, biases folded
    unsigned short* hhi, unsigned short* abhi,
    unsigned short* __restrict__ h0seq,        // L0: bf16 sequence out (else null)
    float* __restrict__ outseq,                // L1: fp32 sequence out (else null)
    float* __restrict__ hn,                    // final h slot
    unsigned* bar)
{
  __shared__ __align__(16) unsigned short WrzS[32*1024]; // 64KB rows0-15=r,16-31=z
  __shared__ __align__(16) unsigned short WhhS[16*1024]; // 32KB
  __shared__ float hloc[16][17];                         // block's fp32 h tile
  __shared__ float zloc[16][17];                         // block's z tile
  __shared__ float part[8][64][9];                       // 8-wave K-combine

  const int bid = blockIdx.x;
  const int g = bid & 3;          // batch group (rows 16g..16g+16)
  const int c = bid >> 2;         // column group (cols 16c..16c+16)
  const int tid = threadIdx.x;
  const int lane = tid & 63, w = tid >> 6;
  const int lr = lane & 15, lq = lane >> 4;

  unsigned* c2  = bar + g*32;            // group counter
  unsigned* cen = bar + 1152 + g*8;      // census[8]
  unsigned xcc = 0, slot = 0, cx = 0, nx = 0;
  bool claim = false;
  unsigned* c1 = nullptr;
  if (tid == 0){
    asm volatile("s_getreg_b32 %0, hwreg(HW_REG_XCC_ID)" : "=s"(xcc));
    xcc &= 7;
    c1 = bar + 128 + (g*8 + (int)xcc)*32;
    slot = cadd(&cen[xcc]);
  }

  // ---- stage weights into LDS (once), XOR-swizzled ----
  #pragma unroll
  for (int j = 0; j < 8; ++j){
    int lin = (tid + j*512) * 8;
    int n = lin >> 10, k = lin & 1023;
    int gr = (n < 16) ? (16*c + n) : (1024 + 16*c + (n - 16));
    short8 v = *reinterpret_cast<const short8*>(&Wrzg[(size_t)gr*1024 + k]);
    *reinterpret_cast<short8*>(&WrzS[(n*1024 + k) ^ ((n&7)<<3)]) = v;
  }
  #pragma unroll
  for (int j = 0; j < 4; ++j){
    int lin = (tid + j*512) * 8;
    int n = lin >> 10, k = lin & 1023;
    short8 v = *reinterpret_cast<const short8*>(&Whhg[(size_t)(16*c + n)*1024 + k]);
    *reinterpret_cast<short8*>(&WhhS[(n*1024 + k) ^ ((n&7)<<3)]) = v;
  }
  // ---- zero local h tile and global h slice (ws is poisoned) ----
  for (int idx = tid; idx < 16*17; idx += 512) ((float*)hloc)[idx] = 0.f;
  if (tid < 128){
    int r = tid >> 3, cp = (tid & 7) * 2;
    cstore_u32(&hhi[(16*g + r)*1024 + 16*c + cp], 0u);
  }
  // ---- init rendezvous: publish h-zeros, finalize census ----
  __syncthreads();
  if (tid == 0){
    __builtin_amdgcn_fence(__ATOMIC_RELEASE, "agent");  // publish my stores
    cadd(c2);
    while (cld(c2) < GBLK) __builtin_amdgcn_s_sleep(1);
    cx = cld(&cen[xcc]);
    claim = (slot == 0);
    unsigned n = 0;
    #pragma unroll
    for (int x = 0; x < 8; ++x) n += (cld(&cen[x + (int)(cen - (bar+1152))]) != 0) ? 0 : 0; // placeholder
    n = 0;
    for (int x = 0; x < 8; ++x) n += (cld(&cen[x]) != 0) ? 1u : 0u;
    nx = n;
  }
  __syncthreads();

  // hierarchical group barrier: per-XCD arrive -> claimant fence -> group ctr
  unsigned p = 0;   // phase counter (1..) — uniform across threads
  auto bar2 = [&](void){
    __syncthreads();
    ++p;
    if (tid == 0){
      cadd(c1);
      if (claim){
        const unsigned t1 = cx * p;
        while (cld(c1) < t1) __builtin_amdgcn_s_sleep(1);
        __builtin_amdgcn_fence(__ATOMIC_RELEASE, "agent");   // one wbl2 per XCD
        cadd(c2);
      }
      const unsigned t2 = GBLK + nx * p;
      while (cld(c2) < t2) __builtin_amdgcn_s_sleep(1);
    }
    __syncthreads();
  };

  const int kb = 128 * w;   // this wave's K-slice

  for (int t = 0; t < Tt; ++t){
    float xcv[4];
    // ================= phase A: rz preact + gates =================
    {
      const unsigned short* xp = XprojRZ + (size_t)t*Bz*2048;
      unsigned xv[4];
      if (w == 0){
        #pragma unroll
        for (int i = 0; i < 4; ++i)
          PLOADU16(xv[i], &xp[(16*g + lq*4 + i)*2048 + 16*c + lr]);
      } else if (w == 1){
        #pragma unroll
        for (int i = 0; i < 4; ++i)
          PLOADU16(xv[i], &xp[(16*g + lq*4 + i)*2048 + 1024 + 16*c + lr]);
      }
      const unsigned short* hhp = hhi + (size_t)(16*g + lr)*1024 + kb + lq*8;
      u32x4 ahv[4];
      #pragma unroll
      for (int s = 0; s < 4; ++s){ CLOAD16(ahv[s], hhp, s) }
      f32x4 accr={0,0,0,0}, accz={0,0,0,0};
      #pragma unroll
      for (int k = 0; k < 4; ++k){
        VMWAIT(3 - k)
        short8 ah = __builtin_bit_cast(short8, ahv[k]);
        short8 br = *reinterpret_cast<const short8*>(
            &WrzS[(lr*1024 + kb + k*32 + lq*8) ^ ((lr&7)<<3)]);
        short8 bz = *reinterpret_cast<const short8*>(
            &WrzS[((16+lr)*1024 + kb + k*32 + lq*8) ^ ((lr&7)<<3)]);
        accr = __builtin_amdgcn_mfma_f32_16x16x32_bf16(ah, br, accr, 0,0,0);
        accz = __builtin_amdgcn_mfma_f32_16x16x32_bf16(ah, bz, accz, 0,0,0);
      }
      #pragma unroll
      for (int i = 0; i < 4; ++i){
        part[w][lane][i]   = accr[i];
        part[w][lane][4+i] = accz[i];
      }
      __syncthreads();
      if (w == 0){          // r-gate + a = h*r
        #pragma unroll
        for (int i = 0; i < 4; ++i){
          float s_ = 0.f;
          #pragma unroll
          for (int ww = 0; ww < 8; ++ww) s_ += part[ww][lane][i];
          int row = lq*4 + i;
          float pr = s_ + bf2f((unsigned short)xv[i]);
          float rg = 1.f / (1.f + __expf(-pr));
          float av = hloc[row][lr] * rg;
          unsigned short hi = f2bf(av);
          unsigned hi2 = (unsigned)__shfl_down((int)hi, 1) & 0xffffu;
          if (!(lane & 1))
            cstore_u32(&abhi[(16*g + row)*1024 + 16*c + lr], (unsigned)hi | (hi2<<16));
        }
      } else if (w == 1){   // z-gate
        #pragma unroll
        for (int i = 0; i < 4; ++i){
          float s_ = 0.f;
          #pragma unroll
          for (int ww = 0; ww < 8; ++ww) s_ += part[ww][lane][4+i];
          int row = lq*4 + i;
          float pz = s_ + bf2f((unsigned short)xv[i]);
          zloc[row][lr] = 1.f / (1.f + __expf(-pz));
        }
      }
      // hoist phase-B input loads: latency hides under the barrier
      if (w == 0){
        const float* xc = XprojC + (size_t)t*Bz*1024;
        #pragma unroll
        for (int i = 0; i < 4; ++i)
          PLOADF(xcv[i], &xc[(16*g + lq*4 + i)*1024 + 16*c + lr]);
      }
    }
    bar2();
    // ================= phase B: cand + state update =================
    {
      const unsigned short* ahp = abhi + (size_t)(16*g + lr)*1024 + kb + lq*8;
      u32x4 ahv[4];
      #pragma unroll
      for (int s = 0; s < 4; ++s){ CLOAD16(ahv[s], ahp, s) }
      f32x4 acc={0,0,0,0};
      #pragma unroll
      for (int k = 0; k < 4; ++k){
        VMWAIT(3 - k)
        short8 ah = __builtin_bit_cast(short8, ahv[k]);
        short8 bb = *reinterpret_cast<const short8*>(
            &WhhS[(lr*1024 + kb + k*32 + lq*8) ^ ((lr&7)<<3)]);
        acc = __builtin_amdgcn_mfma_f32_16x16x32_bf16(ah, bb, acc, 0,0,0);
      }
      #pragma unroll
      for (int i = 0; i < 4; ++i) part[w][lane][i] = acc[i];
      __syncthreads();
      if (w == 0){
        #pragma unroll
        for (int i = 0; i < 4; ++i){
          float s_ = 0.f;
          #pragma unroll
          for (int ww = 0; ww < 8; ++ww) s_ += part[ww][lane][i];
          int row = lq*4 + i;
          int grow = 16*g + row, gcol = 16*c + lr;
          float pre = s_ + xcv[i];
          float cand = tanhf(pre);
          float zg = zloc[row][lr];
          float h  = hloc[row][lr];
          float hnew = zg*h + (1.f - zg)*cand;
          hloc[row][lr] = hnew;
          unsigned short hi = f2bf(hnew);
          unsigned hi2 = (unsigned)__shfl_down((int)hi, 1) & 0xffffu;
          float hnew2 = __shfl_down(hnew, 1);
          if (!(lane & 1)){
            cstore_u32(&hhi[(size_t)grow*1024 + gcol], (unsigned)hi | (hi2<<16));
            if (h0seq)
              cstore_u32(&h0seq[(size_t)t*(Bz*Hh) + grow*1024 + gcol],
                         (unsigned)hi | (hi2<<16));
            if (outseq){
              float2 pr2 = {hnew, hnew2};
              cstore_u64(&outseq[(size_t)t*(Bz*Hh) + grow*1024 + gcol],
                         __builtin_bit_cast(u64, pr2));
            }
            if (t == Tt-1){
              float2 pr2 = {hnew, hnew2};
              cstore_u64(&hn[(size_t)grow*1024 + gcol], __builtin_bit_cast(u64, pr2));
            }
          }
        }
      }
    }
    bar2();
  }
}

// ---------------- host ----------------

extern "C" void kernel_launch(void* const* d_in, const int* in_sizes, int n_in,
                              void* d_out, int out_size, void* d_ws, size_t ws_size,
                              hipStream_t stream)
{
  (void)in_sizes; (void)n_in; (void)out_size; (void)ws_size;
  const float* X     = (const float*)d_in[0];
  const float* Wxrz0 = (const float*)d_in[1];
  const float* bxrz0 = (const float*)d_in[2];
  const float* Whrz0 = (const float*)d_in[3];
  const float* bhrz0 = (const float*)d_in[4];
  const float* Wxh0  = (const float*)d_in[5];
  const float* bxh0  = (const float*)d_in[6];
  const float* Whh0  = (const float*)d_in[7];
  const float* bhh0  = (const float*)d_in[8];
  const float* Wxrz1 = (const float*)d_in[9];
  const float* bxrz1 = (const float*)d_in[10];
  const float* Whrz1 = (const float*)d_in[11];
  const float* bhrz1 = (const float*)d_in[12];
  const float* Wxh1  = (const float*)d_in[13];
  const float* bxh1  = (const float*)d_in[14];
  const float* Whh1  = (const float*)d_in[15];
  const float* bhh1  = (const float*)d_in[16];

  char* p = (char*)d_ws;
  auto carve = [&](size_t bytes)->char*{
    char* r = p; p += (bytes + 255) & ~(size_t)255; return r;
  };
  unsigned short* Xbf    = (unsigned short*)carve((size_t)Mrows*512*2);
  unsigned short* W0t    = (unsigned short*)carve((size_t)3072*512*2);
  unsigned short* W1t    = (unsigned short*)carve((size_t)3072*1024*2);
  unsigned short* Whrz0t = (unsigned short*)carve((size_t)2048*1024*2);
  unsigned short* Whh0t  = (unsigned short*)carve((size_t)1024*1024*2);
  unsigned short* Whrz1t = (unsigned short*)carve((size_t)2048*1024*2);
  unsigned short* Whh1t  = (unsigned short*)carve((size_t)1024*1024*2);
  float* bias0 = (float*)carve(3072*4);
  float* bias1 = (float*)carve(3072*4);
  unsigned short* XprojRZ = (unsigned short*)carve((size_t)Mrows*2048*2);
  float*          XprojC  = (float*)carve((size_t)Mrows*1024*4);
  unsigned short* H0seq   = (unsigned short*)carve((size_t)Mrows*1024*2);
  unsigned short* hhi  = (unsigned short*)carve(Bz*Hh*2);
  unsigned short* abhi = (unsigned short*)carve(Bz*Hh*2);
  unsigned* bar = (unsigned*)carve(16384);  // L0 @ bar, L1 @ bar+2048 (u32)

  hipMemsetAsync(bar, 0, 16384, stream);

  k_cvt_bf16<<<2048,256,0,stream>>>(X, Xbf, Mrows*512/4);
  k_transpose_bf16<<<dim3(8,32), 256,0,stream>>>(Wxrz0, W0t, 512, 2048);
  k_transpose_bf16<<<dim3(8,16), 256,0,stream>>>(Wxh0,  W0t + (size_t)2048*512, 512, 1024);
  k_transpose_bf16<<<dim3(16,32),256,0,stream>>>(Whrz0, Whrz0t, 1024, 2048);
  k_transpose_bf16<<<dim3(16,16),256,0,stream>>>(Whh0,  Whh0t, 1024, 1024);
  k_transpose_bf16<<<dim3(16,32),256,0,stream>>>(Wxrz1, W1t, 1024, 2048);
  k_transpose_bf16<<<dim3(16,16),256,0,stream>>>(Wxh1,  W1t + (size_t)2048*1024, 1024, 1024);
  k_transpose_bf16<<<dim3(16,32),256,0,stream>>>(Whrz1, Whrz1t, 1024, 2048);
  k_transpose_bf16<<<dim3(16,16),256,0,stream>>>(Whh1,  Whh1t, 1024, 1024);
  k_bias_fold<<<12,256,0,stream>>>(bxrz0, bhrz0, bxh0, bhh0, bias0);
  k_bias_fold<<<12,256,0,stream>>>(bxrz1, bhrz1, bxh1, bhh1, bias1);

  float* out = (float*)d_out;
  float* hn0 = out + (size_t)Mrows*Hh;
  float* hn1 = hn0 + Bz*Hh;

  // ---- layer 0 ----
  k_xproj_gemm<<<dim3(24,256),256,0,stream>>>(Xbf, W0t, bias0, XprojRZ, XprojC, 512);
  k_gru_layer<<<256,512,0,stream>>>(Whrz0t, Whh0t, XprojRZ, XprojC,
                                    hhi, abhi,
                                    H0seq, nullptr, hn0, bar);
  // ---- layer 1 ----
  k_xproj_gemm<<<dim3(24,256),256,0,stream>>>(H0seq, W1t, bias1, XprojRZ, XprojC, 1024);
  k_gru_layer<<<256,512,0,stream>>>(Whrz1t, Whh1t, XprojRZ, XprojC,
                                    hhi, abhi,
                                    nullptr, out, hn1, bar + 2048);
}

// Round 15
// 6703.069 us; speedup vs baseline: 2.2164x; 1.1752x over previous
//
#include <hip/hip_runtime.h>
#include <hip/hip_bf16.h>

// GRU: T=512, B=64, Cin=512, H=1024, 2 layers.
// Round 15: r14 + 8-way epilogue split + busy polls. r14's step = ~3us
// barrier + ~1us load latency + ~2us epilogue (waves 0-1 only, 6 idle).
// Split gate/update epilogues across all 8 waves (wave w<4: r-row i=w and
// phase-B row i=w; waves 4-7: z-row i=w-4); scalar xv/xcv loads drop 4->1
// per lane. Sync structure (hierarchical claimant fence) byte-identical.

#define Hh   1024
#define Bz   64
#define Tt   512
#define Mrows (Tt*Bz)   // 32768
#define GBLK 64         // blocks per batch-group

typedef __attribute__((ext_vector_type(8))) short short8;
typedef __attribute__((ext_vector_type(4))) float f32x4;
typedef __attribute__((ext_vector_type(4))) unsigned int u32x4;
typedef unsigned long long u64;

__device__ __forceinline__ unsigned short f2bf(float f){
  unsigned u = __builtin_bit_cast(unsigned, f);
  u += 0x7fffu + ((u >> 16) & 1u);          // round-to-nearest-even
  return (unsigned short)(u >> 16);
}
__device__ __forceinline__ float bf2f(unsigned short s){
  unsigned u = ((unsigned)s) << 16;
  return __builtin_bit_cast(float, u);
}

// write-through coherent stores (agent scope, relaxed)
__device__ __forceinline__ void cstore_u32(void* p, unsigned v){
  __hip_atomic_store((unsigned*)p, v, __ATOMIC_RELAXED, __HIP_MEMORY_SCOPE_AGENT);
}
__device__ __forceinline__ void cstore_u64(void* p, u64 v){
  __hip_atomic_store((u64*)p, v, __ATOMIC_RELAXED, __HIP_MEMORY_SCOPE_AGENT);
}
__device__ __forceinline__ unsigned cld(unsigned* p){
  return __hip_atomic_load(p, __ATOMIC_RELAXED, __HIP_MEMORY_SCOPE_AGENT);
}
__device__ __forceinline__ unsigned cadd(unsigned* p){
  return __hip_atomic_fetch_add(p, 1u, __ATOMIC_RELAXED, __HIP_MEMORY_SCOPE_AGENT);
}

__device__ __forceinline__ void gload16(const void* g, void* l){
  __builtin_amdgcn_global_load_lds(
      (const __attribute__((address_space(1))) unsigned int*)g,
      (__attribute__((address_space(3))) unsigned int*)l, 16, 0, 0);
}

// ---- pipelined loads ----
#define CLOAD16(dst, base, kk) \
  asm volatile("global_load_dwordx4 %0, %1, off offset:%c2 sc0 sc1" \
               : "=v"(dst) : "v"(base), "i"((kk)*64));
#define PLOADF(dst, addr) \
  asm volatile("global_load_dword %0, %1, off" : "=v"(dst) : "v"(addr));
#define PLOADU16(dst, addr) \
  asm volatile("global_load_ushort %0, %1, off" : "=v"(dst) : "v"(addr));
#define VMWAIT(n) \
  asm volatile("s_waitcnt vmcnt(%c0)" :: "i"(n) : "memory"); \
  __builtin_amdgcn_sched_barrier(0);

// ---------------- prep kernels ----------------

__global__ __launch_bounds__(256) void k_cvt_bf16(const float* __restrict__ src,
                                                  unsigned short* __restrict__ dst, int n4){
  int i = blockIdx.x*blockDim.x + threadIdx.x;
  int stride = gridDim.x*blockDim.x;
  for (; i < n4; i += stride){
    float4 v = reinterpret_cast<const float4*>(src)[i];
    ushort4 o; o.x=f2bf(v.x); o.y=f2bf(v.y); o.z=f2bf(v.z); o.w=f2bf(v.w);
    reinterpret_cast<ushort4*>(dst)[i] = o;
  }
}

// fp32 (K,N) -> bf16 (N,K), 64x64 LDS tile
__global__ __launch_bounds__(256) void k_transpose_bf16(const float* __restrict__ src,
                                                        unsigned short* __restrict__ dst,
                                                        int K, int N){
  __shared__ float tile[64][65];
  int k0 = blockIdx.x * 64, n0 = blockIdx.y * 64;
  int t = threadIdx.x;
  int r = t >> 4, c4 = (t & 15) << 2;
  #pragma unroll
  for (int j = 0; j < 4; ++j){
    const float4 v = *reinterpret_cast<const float4*>(&src[(size_t)(k0 + r + j*16) * N + n0 + c4]);
    tile[r+j*16][c4+0]=v.x; tile[r+j*16][c4+1]=v.y;
    tile[r+j*16][c4+2]=v.z; tile[r+j*16][c4+3]=v.w;
  }
  __syncthreads();
  #pragma unroll
  for (int j = 0; j < 4; ++j){
    int nn = r + j*16;
    ushort4 o;
    o.x = f2bf(tile[c4+0][nn]); o.y = f2bf(tile[c4+1][nn]);
    o.z = f2bf(tile[c4+2][nn]); o.w = f2bf(tile[c4+3][nn]);
    *reinterpret_cast<ushort4*>(&dst[(size_t)(n0+nn)*K + k0 + c4]) = o;
  }
}

__global__ void k_bias_fold(const float* __restrict__ a, const float* __restrict__ b,
                            const float* __restrict__ c, const float* __restrict__ d,
                            float* __restrict__ out){
  int i = blockIdx.x*blockDim.x + threadIdx.x;
  if (i < 2048) out[i] = a[i] + b[i];
  else if (i < 3072) out[i] = c[i-2048] + d[i-2048];
}

// ---------------- big x-projection GEMM ----------------
__global__ __launch_bounds__(256) void k_xproj_gemm(
    const unsigned short* __restrict__ A, const unsigned short* __restrict__ Bt,
    const float* __restrict__ bias, unsigned short* __restrict__ outRZ,
    float* __restrict__ outC, int K)
{
  __shared__ __align__(16) unsigned short As[128*32];
  __shared__ __align__(16) unsigned short Bs[128*32];
  const int nb = blockIdx.x, mb = blockIdx.y;
  const int m0 = mb*128, n0 = nb*128;
  const int t = threadIdx.x, lane = t & 63, w = t >> 6;
  const int wr = w >> 1, wc = w & 1;
  const int lr = lane & 15, lq = lane >> 4;
  const int sr = t >> 2, scg = t & 3;
  f32x4 acc[4][4];
  const f32x4 zero4 = {0.f,0.f,0.f,0.f};
  #pragma unroll
  for (int mt=0;mt<4;++mt)
    #pragma unroll
    for (int nt=0;nt<4;++nt) acc[mt][nt] = zero4;

  const unsigned short* ga0 = &A [(size_t)(m0 + sr     )*K + scg*8];
  const unsigned short* ga1 = &A [(size_t)(m0 + sr + 64)*K + scg*8];
  const unsigned short* gb0 = &Bt[(size_t)(n0 + sr     )*K + scg*8];
  const unsigned short* gb1 = &Bt[(size_t)(n0 + sr + 64)*K + scg*8];
  char* lA = (char*)As + w*1024;
  char* lB = (char*)Bs + w*1024;
  const int kiters = K >> 5;
  for (int kt = 0; kt < kiters; ++kt){
    __syncthreads();
    gload16(ga0 + kt*32, lA);
    gload16(ga1 + kt*32, lA + 4096);
    gload16(gb0 + kt*32, lB);
    gload16(gb1 + kt*32, lB + 4096);
    asm volatile("s_waitcnt vmcnt(0)" ::: "memory");
    __syncthreads();
    short8 af[4], bfr[4];
    #pragma unroll
    for (int mt=0; mt<4; ++mt)
      af[mt] = *reinterpret_cast<const short8*>(&As[(wr*64 + mt*16 + lr)*32 + lq*8]);
    #pragma unroll
    for (int nt=0; nt<4; ++nt)
      bfr[nt] = *reinterpret_cast<const short8*>(&Bs[(wc*64 + nt*16 + lr)*32 + lq*8]);
    #pragma unroll
    for (int mt=0; mt<4; ++mt)
      #pragma unroll
      for (int nt=0; nt<4; ++nt)
        acc[mt][nt] = __builtin_amdgcn_mfma_f32_16x16x32_bf16(af[mt], bfr[nt], acc[mt][nt], 0,0,0);
  }
  const bool isRZ = (n0 < 2048);
  #pragma unroll
  for (int mt=0;mt<4;++mt){
    #pragma unroll
    for (int nt=0;nt<4;++nt){
      int gn = n0 + wc*64 + nt*16 + lr;
      float bv = bias[gn];
      #pragma unroll
      for (int i=0;i<4;++i){
        int gm = m0 + wr*64 + mt*16 + lq*4 + i;
        float v = acc[mt][nt][i] + bv;
        if (isRZ) outRZ[(size_t)gm*2048 + gn] = f2bf(v);
        else      outC [(size_t)gm*1024 + (gn - 2048)] = v;
      }
    }
  }
}

// ---------------- persistent per-layer recurrent kernel ----------------
// 256 blocks x 512 threads. Block (g,c): batch rows [16g,16g+16) x cols
// [16c,16c+16). Cross-block state: plain-bf16 h and a via sc0sc1 ld/st.
// Hierarchical publish (r14). Epilogues split across all 8 waves:
// wave w<4: r-gate row i=w (phase A) + update row i=w (phase B);
// waves 4-7: z-gate row i=w-4 (phase A).
__global__ __launch_bounds__(512) void k_gru_layer(
    const unsigned short* __restrict__ Wrzg,   // (2048,1024) bf16
    const unsigned short* __restrict__ Whhg,   // (1024,1024) bf16
    const unsigned short* __restrict__ XprojRZ,// (T,64,2048) bf16, biases folded
    const float* __restrict__ XprojC,          // (T,64,1024) fp32, biases folded
    unsigned short* hhi, unsigned short* abhi,
    unsigned short* __restrict__ h0seq,        // L0: bf16 sequence out (else null)
    float* __restrict__ outseq,                // L1: fp32 sequence out (else null)
    float* __restrict__ hn,                    // final h slot
    unsigned* bar)
{
  __shared__ __align__(16) unsigned short WrzS[32*1024]; // 64KB rows0-15=r,16-31=z
  __shared__ __align__(16) unsigned short WhhS[16*1024]; // 32KB
  __shared__ float hloc[16][17];                         // block's fp32 h tile
  __shared__ float zloc[16][17];                         // block's z tile
  __shared__ float part[8][64][9];                       // 8-wave K-combine

  const int bid = blockIdx.x;
  const int g = bid & 3;          // batch group (rows 16g..16g+16)
  const int c = bid >> 2;         // column group (cols 16c..16c+16)
  const int tid = threadIdx.x;
  const int lane = tid & 63, w = tid >> 6;
  const int lr = lane & 15, lq = lane >> 4;

  unsigned* c2  = bar + g*32;            // group counter
  unsigned* cen = bar + 1152 + g*8;      // census[8]
  unsigned xcc = 0, slot = 0, cx = 0, nx = 0;
  bool claim = false;
  unsigned* c1 = nullptr;
  if (tid == 0){
    asm volatile("s_getreg_b32 %0, hwreg(HW_REG_XCC_ID)" : "=s"(xcc));
    xcc &= 7;
    c1 = bar + 128 + (g*8 + (int)xcc)*32;
    slot = cadd(&cen[xcc]);
  }

  // ---- stage weights into LDS (once), XOR-swizzled ----
  #pragma unroll
  for (int j = 0; j < 8; ++j){
    int lin = (tid + j*512) * 8;
    int n = lin >> 10, k = lin & 1023;
    int gr = (n < 16) ? (16*c + n) : (1024 + 16*c + (n - 16));
    short8 v = *reinterpret_cast<const short8*>(&Wrzg[(size_t)gr*1024 + k]);
    *reinterpret_cast<short8*>(&WrzS[(n*1024 + k) ^ ((n&7)<<3)]) = v;
  }
  #pragma unroll
  for (int j = 0; j < 4; ++j){
    int lin = (tid + j*512) * 8;
    int n = lin >> 10, k = lin & 1023;
    short8 v = *reinterpret_cast<const short8*>(&Whhg[(size_t)(16*c + n)*1024 + k]);
    *reinterpret_cast<short8*>(&WhhS[(n*1024 + k) ^ ((n&7)<<3)]) = v;
  }
  // ---- zero local h tile and global h slice (ws is poisoned) ----
  for (int idx = tid; idx < 16*17; idx += 512) ((float*)hloc)[idx] = 0.f;
  if (tid < 128){
    int r = tid >> 3, cp = (tid & 7) * 2;
    cstore_u32(&hhi[(16*g + r)*1024 + 16*c + cp], 0u);
  }
  // ---- init rendezvous: publish h-zeros, finalize census ----
  __syncthreads();
  if (tid == 0){
    __builtin_amdgcn_fence(__ATOMIC_RELEASE, "agent");  // publish my stores
    cadd(c2);
    while (cld(c2) < GBLK) __builtin_amdgcn_s_sleep(1);
    cx = cld(&cen[xcc]);
    claim = (slot == 0);
    unsigned n = 0;
    for (int x = 0; x < 8; ++x) n += (cld(&cen[x]) != 0) ? 1u : 0u;
    nx = n;
  }
  __syncthreads();

  // hierarchical group barrier: per-XCD arrive -> claimant fence -> group ctr
  unsigned p = 0;   // phase counter (1..) — uniform across threads
  auto bar2 = [&](void){
    __syncthreads();
    ++p;
    if (tid == 0){
      cadd(c1);
      if (claim){
        const unsigned t1 = cx * p;
        while (cld(c1) < t1) {}
        __builtin_amdgcn_fence(__ATOMIC_RELEASE, "agent");   // one wbl2 per XCD
        cadd(c2);
      }
      const unsigned t2 = GBLK + nx * p;
      while (cld(c2) < t2) {}
    }
    __syncthreads();
  };

  const int kb = 128 * w;          // this wave's K-slice
  const int ei = w & 3;            // this wave's epilogue row-subindex
  const bool isR = (w < 4);        // r-waves vs z-waves
  const int erow = lq*4 + ei;      // epilogue row within the 16-row tile

  for (int t = 0; t < Tt; ++t){
    float xcv;
    // ================= phase A: rz preact + gates =================
    {
      const unsigned short* xp = XprojRZ + (size_t)t*Bz*2048;
      unsigned xv;
      PLOADU16(xv, &xp[(16*g + erow)*2048 + (isR ? 0 : 1024) + 16*c + lr]);
      const unsigned short* hhp = hhi + (size_t)(16*g + lr)*1024 + kb + lq*8;
      u32x4 ahv[4];
      #pragma unroll
      for (int s = 0; s < 4; ++s){ CLOAD16(ahv[s], hhp, s) }
      f32x4 accr={0,0,0,0}, accz={0,0,0,0};
      #pragma unroll
      for (int k = 0; k < 4; ++k){
        VMWAIT(3 - k)
        short8 ah = __builtin_bit_cast(short8, ahv[k]);
        short8 br = *reinterpret_cast<const short8*>(
            &WrzS[(lr*1024 + kb + k*32 + lq*8) ^ ((lr&7)<<3)]);
        short8 bz = *reinterpret_cast<const short8*>(
            &WrzS[((16+lr)*1024 + kb + k*32 + lq*8) ^ ((lr&7)<<3)]);
        accr = __builtin_amdgcn_mfma_f32_16x16x32_bf16(ah, br, accr, 0,0,0);
        accz = __builtin_amdgcn_mfma_f32_16x16x32_bf16(ah, bz, accz, 0,0,0);
      }
      #pragma unroll
      for (int i = 0; i < 4; ++i){
        part[w][lane][i]   = accr[i];
        part[w][lane][4+i] = accz[i];
      }
      __syncthreads();
      if (isR){             // r-gate + a = h*r, row ei
        float s_ = 0.f;
        #pragma unroll
        for (int ww = 0; ww < 8; ++ww) s_ += part[ww][lane][ei];
        float pr = s_ + bf2f((unsigned short)xv);
        float rg = 1.f / (1.f + __expf(-pr));
        float av = hloc[erow][lr] * rg;
        unsigned short hi = f2bf(av);
        unsigned hi2 = (unsigned)__shfl_down((int)hi, 1) & 0xffffu;
        if (!(lane & 1))
          cstore_u32(&abhi[(16*g + erow)*1024 + 16*c + lr], (unsigned)hi | (hi2<<16));
        // hoist phase-B xc load: hides under the barrier
        const float* xc = XprojC + (size_t)t*Bz*1024;
        PLOADF(xcv, &xc[(16*g + erow)*1024 + 16*c + lr]);
      } else {              // z-gate, row ei
        float s_ = 0.f;
        #pragma unroll
        for (int ww = 0; ww < 8; ++ww) s_ += part[ww][lane][4+ei];
        float pz = s_ + bf2f((unsigned short)xv);
        zloc[erow][lr] = 1.f / (1.f + __expf(-pz));
      }
    }
    bar2();
    // ================= phase B: cand + state update =================
    {
      const unsigned short* ahp = abhi + (size_t)(16*g + lr)*1024 + kb + lq*8;
      u32x4 ahv[4];
      #pragma unroll
      for (int s = 0; s < 4; ++s){ CLOAD16(ahv[s], ahp, s) }
      f32x4 acc={0,0,0,0};
      #pragma unroll
      for (int k = 0; k < 4; ++k){
        VMWAIT(3 - k)
        short8 ah = __builtin_bit_cast(short8, ahv[k]);
        short8 bb = *reinterpret_cast<const short8*>(
            &WhhS[(lr*1024 + kb + k*32 + lq*8) ^ ((lr&7)<<3)]);
        acc = __builtin_amdgcn_mfma_f32_16x16x32_bf16(ah, bb, acc, 0,0,0);
      }
      #pragma unroll
      for (int i = 0; i < 4; ++i) part[w][lane][i] = acc[i];
      __syncthreads();
      if (isR){             // state update, row ei
        float s_ = 0.f;
        #pragma unroll
        for (int ww = 0; ww < 8; ++ww) s_ += part[ww][lane][ei];
        int grow = 16*g + erow, gcol = 16*c + lr;
        float pre = s_ + xcv;
        float cand = tanhf(pre);
        float zg = zloc[erow][lr];
        float h  = hloc[erow][lr];
        float hnew = zg*h + (1.f - zg)*cand;
        hloc[erow][lr] = hnew;
        unsigned short hi = f2bf(hnew);
        unsigned hi2 = (unsigned)__shfl_down((int)hi, 1) & 0xffffu;
        float hnew2 = __shfl_down(hnew, 1);
        if (!(lane & 1)){
          cstore_u32(&hhi[(size_t)grow*1024 + gcol], (unsigned)hi | (hi2<<16));
          if (h0seq)
            cstore_u32(&h0seq[(size_t)t*(Bz*Hh) + grow*1024 + gcol],
                       (unsigned)hi | (hi2<<16));
          if (outseq){
            float2 pr2 = {hnew, hnew2};
            cstore_u64(&outseq[(size_t)t*(Bz*Hh) + grow*1024 + gcol],
                       __builtin_bit_cast(u64, pr2));
          }
          if (t == Tt-1){
            float2 pr2 = {hnew, hnew2};
            cstore_u64(&hn[(size_t)grow*1024 + gcol], __builtin_bit_cast(u64, pr2));
          }
        }
      }
    }
    bar2();
  }
}

// ---------------- host ----------------

extern "C" void kernel_launch(void* const* d_in, const int* in_sizes, int n_in,
                              void* d_out, int out_size, void* d_ws, size_t ws_size,
                              hipStream_t stream)
{
  (void)in_sizes; (void)n_in; (void)out_size; (void)ws_size;
  const float* X     = (const float*)d_in[0];
  const float* Wxrz0 = (const float*)d_in[1];
  const float* bxrz0 = (const float*)d_in[2];
  const float* Whrz0 = (const float*)d_in[3];
  const float* bhrz0 = (const float*)d_in[4];
  const float* Wxh0  = (const float*)d_in[5];
  const float* bxh0  = (const float*)d_in[6];
  const float* Whh0  = (const float*)d_in[7];
  const float* bhh0  = (const float*)d_in[8];
  const float* Wxrz1 = (const float*)d_in[9];
  const float* bxrz1 = (const float*)d_in[10];
  const float* Whrz1 = (const float*)d_in[11];
  const float* bhrz1 = (const float*)d_in[12];
  const float* Wxh1  = (const float*)d_in[13];
  const float* bxh1  = (const float*)d_in[14];
  const float* Whh1  = (const float*)d_in[15];
  const float* bhh1  = (const float*)d_in[16];

  char* p = (char*)d_ws;
  auto carve = [&](size_t bytes)->char*{
    char* r = p; p += (bytes + 255) & ~(size_t)255; return r;
  };
  unsigned short* Xbf    = (unsigned short*)carve((size_t)Mrows*512*2);
  unsigned short* W0t    = (unsigned short*)carve((size_t)3072*512*2);
  unsigned short* W1t    = (unsigned short*)carve((size_t)3072*1024*2);
  unsigned short* Whrz0t = (unsigned short*)carve((size_t)2048*1024*2);
  unsigned short* Whh0t  = (unsigned short*)carve((size_t)1024*1024*2);
  unsigned short* Whrz1t = (unsigned short*)carve((size_t)2048*1024*2);
  unsigned short* Whh1t  = (unsigned short*)carve((size_t)1024*1024*2);
  float* bias0 = (float*)carve(3072*4);
  float* bias1 = (float*)carve(3072*4);
  unsigned short* XprojRZ = (unsigned short*)carve((size_t)Mrows*2048*2);
  float*          XprojC  = (float*)carve((size_t)Mrows*1024*4);
  unsigned short* H0seq   = (unsigned short*)carve((size_t)Mrows*1024*2);
  unsigned short* hhi  = (unsigned short*)carve(Bz*Hh*2);
  unsigned short* abhi = (unsigned short*)carve(Bz*Hh*2);
  unsigned* bar = (unsigned*)carve(16384);  // L0 @ bar, L1 @ bar+2048 (u32)

  hipMemsetAsync(bar, 0, 16384, stream);

  k_cvt_bf16<<<2048,256,0,stream>>>(X, Xbf, Mrows*512/4);
  k_transpose_bf16<<<dim3(8,32), 256,0,stream>>>(Wxrz0, W0t, 512, 2048);
  k_transpose_bf16<<<dim3(8,16), 256,0,stream>>>(Wxh0,  W0t + (size_t)2048*512, 512, 1024);
  k_transpose_bf16<<<dim3(16,32),256,0,stream>>>(Whrz0, Whrz0t, 1024, 2048);
  k_transpose_bf16<<<dim3(16,16),256,0,stream>>>(Whh0,  Whh0t, 1024, 1024);
  k_transpose_bf16<<<dim3(16,32),256,0,stream>>>(Wxrz1, W1t, 1024, 2048);
  k_transpose_bf16<<<dim3(16,16),256,0,stream>>>(Wxh1,  W1t + (size_t)2048*1024, 1024, 1024);
  k_transpose_bf16<<<dim3(16,32),256,0,stream>>>(Whrz1, Whrz1t, 1024, 2048);
  k_transpose_bf16<<<dim3(16,16),256,0,stream>>>(Whh1,  Whh1t, 1024, 1024);
  k_bias_fold<<<12,256,0,stream>>>(bxrz0, bhrz0, bxh0, bhh0, bias0);
  k_bias_fold<<<12,256,0,stream>>>(bxrz1, bhrz1, bxh1, bhh1, bias1);

  float* out = (float*)d_out;
  float* hn0 = out + (size_t)Mrows*Hh;
  float* hn1 = hn0 + Bz*Hh;

  // ---- layer 0 ----
  k_xproj_gemm<<<dim3(24,256),256,0,stream>>>(Xbf, W0t, bias0, XprojRZ, XprojC, 512);
  k_gru_layer<<<256,512,0,stream>>>(Whrz0t, Whh0t, XprojRZ, XprojC,
                                    hhi, abhi,
                                    H0seq, nullptr, hn0, bar);
  // ---- layer 1 ----
  k_xproj_gemm<<<dim3(24,256),256,0,stream>>>(H0seq, W1t, bias1, XprojRZ, XprojC, 1024);
  k_gru_layer<<<256,512,0,stream>>>(Whrz1t, Whh1t, XprojRZ, XprojC,
                                    hhi, abhi,
                                    nullptr, out, hn1, bar + 2048);
}

// Round 16
// 6668.913 us; speedup vs baseline: 2.2278x; 1.0051x over previous
//
#include <hip/hip_runtime.h>
#include <hip/hip_bf16.h>

// GRU: T=512, B=64, Cin=512, H=1024, 2 layers.
// Round 16: r15 + deferred output stores + xv prefetch. Outputs (h0seq/
// outseq/hn) are not consumed in-kernel: stash step t's values in registers
// and store them at the TOP of the next phase B (~2us before the next fence,
// so the claimant's wbl2 sees no fresh pending write-throughs from them).
// Deferred stores + prefetch are inline-asm at pinned positions; vmcnt
// ladders adjusted per wave role (isR: VMWAIT(5-k) in B; z: VMWAIT(4-k)).
// Sync structure (hierarchical claimant fence) byte-identical to r14/r15.

#define Hh   1024
#define Bz   64
#define Tt   512
#define Mrows (Tt*Bz)   // 32768
#define GBLK 64         // blocks per batch-group

typedef __attribute__((ext_vector_type(8))) short short8;
typedef __attribute__((ext_vector_type(4))) float f32x4;
typedef __attribute__((ext_vector_type(4))) unsigned int u32x4;
typedef unsigned long long u64;

__device__ __forceinline__ unsigned short f2bf(float f){
  unsigned u = __builtin_bit_cast(unsigned, f);
  u += 0x7fffu + ((u >> 16) & 1u);          // round-to-nearest-even
  return (unsigned short)(u >> 16);
}
__device__ __forceinline__ float bf2f(unsigned short s){
  unsigned u = ((unsigned)s) << 16;
  return __builtin_bit_cast(float, u);
}

// write-through coherent stores (agent scope, relaxed)
__device__ __forceinline__ void cstore_u32(void* p, unsigned v){
  __hip_atomic_store((unsigned*)p, v, __ATOMIC_RELAXED, __HIP_MEMORY_SCOPE_AGENT);
}
__device__ __forceinline__ void cstore_u64(void* p, u64 v){
  __hip_atomic_store((u64*)p, v, __ATOMIC_RELAXED, __HIP_MEMORY_SCOPE_AGENT);
}
__device__ __forceinline__ unsigned cld(unsigned* p){
  return __hip_atomic_load(p, __ATOMIC_RELAXED, __HIP_MEMORY_SCOPE_AGENT);
}
__device__ __forceinline__ unsigned cadd(unsigned* p){
  return __hip_atomic_fetch_add(p, 1u, __ATOMIC_RELAXED, __HIP_MEMORY_SCOPE_AGENT);
}

__device__ __forceinline__ void gload16(const void* g, void* l){
  __builtin_amdgcn_global_load_lds(
      (const __attribute__((address_space(1))) unsigned int*)g,
      (__attribute__((address_space(3))) unsigned int*)l, 16, 0, 0);
}

// ---- pinned-position asm memory ops (vmcnt-ladder accounted) ----
#define CLOAD16(dst, base, kk) \
  asm volatile("global_load_dwordx4 %0, %1, off offset:%c2 sc0 sc1" \
               : "=v"(dst) : "v"(base), "i"((kk)*64));
#define PLOADF(dst, addr) \
  asm volatile("global_load_dword %0, %1, off" : "=v"(dst) : "v"(addr));
#define PLOADU16(dst, addr) \
  asm volatile("global_load_ushort %0, %1, off" : "=v"(dst) : "v"(addr));
#define ASTORE32(addr, val) \
  asm volatile("global_store_dword %0, %1, off sc0 sc1" :: "v"(addr), "v"(val) : "memory");
#define ASTORE64(addr, val) \
  asm volatile("global_store_dwordx2 %0, %1, off sc0 sc1" :: "v"(addr), "v"(val) : "memory");
#define VMWAIT(n) \
  asm volatile("s_waitcnt vmcnt(%c0)" :: "i"(n) : "memory"); \
  __builtin_amdgcn_sched_barrier(0);

// ---------------- prep kernels ----------------

__global__ __launch_bounds__(256) void k_cvt_bf16(const float* __restrict__ src,
                                                  unsigned short* __restrict__ dst, int n4){
  int i = blockIdx.x*blockDim.x + threadIdx.x;
  int stride = gridDim.x*blockDim.x;
  for (; i < n4; i += stride){
    float4 v = reinterpret_cast<const float4*>(src)[i];
    ushort4 o; o.x=f2bf(v.x); o.y=f2bf(v.y); o.z=f2bf(v.z); o.w=f2bf(v.w);
    reinterpret_cast<ushort4*>(dst)[i] = o;
  }
}

// fp32 (K,N) -> bf16 (N,K), 64x64 LDS tile
__global__ __launch_bounds__(256) void k_transpose_bf16(const float* __restrict__ src,
                                                        unsigned short* __restrict__ dst,
                                                        int K, int N){
  __shared__ float tile[64][65];
  int k0 = blockIdx.x * 64, n0 = blockIdx.y * 64;
  int t = threadIdx.x;
  int r = t >> 4, c4 = (t & 15) << 2;
  #pragma unroll
  for (int j = 0; j < 4; ++j){
    const float4 v = *reinterpret_cast<const float4*>(&src[(size_t)(k0 + r + j*16) * N + n0 + c4]);
    tile[r+j*16][c4+0]=v.x; tile[r+j*16][c4+1]=v.y;
    tile[r+j*16][c4+2]=v.z; tile[r+j*16][c4+3]=v.w;
  }
  __syncthreads();
  #pragma unroll
  for (int j = 0; j < 4; ++j){
    int nn = r + j*16;
    ushort4 o;
    o.x = f2bf(tile[c4+0][nn]); o.y = f2bf(tile[c4+1][nn]);
    o.z = f2bf(tile[c4+2][nn]); o.w = f2bf(tile[c4+3][nn]);
    *reinterpret_cast<ushort4*>(&dst[(size_t)(n0+nn)*K + k0 + c4]) = o;
  }
}

__global__ void k_bias_fold(const float* __restrict__ a, const float* __restrict__ b,
                            const float* __restrict__ c, const float* __restrict__ d,
                            float* __restrict__ out){
  int i = blockIdx.x*blockDim.x + threadIdx.x;
  if (i < 2048) out[i] = a[i] + b[i];
  else if (i < 3072) out[i] = c[i-2048] + d[i-2048];
}

// ---------------- big x-projection GEMM ----------------
__global__ __launch_bounds__(256) void k_xproj_gemm(
    const unsigned short* __restrict__ A, const unsigned short* __restrict__ Bt,
    const float* __restrict__ bias, unsigned short* __restrict__ outRZ,
    float* __restrict__ outC, int K)
{
  __shared__ __align__(16) unsigned short As[128*32];
  __shared__ __align__(16) unsigned short Bs[128*32];
  const int nb = blockIdx.x, mb = blockIdx.y;
  const int m0 = mb*128, n0 = nb*128;
  const int t = threadIdx.x, lane = t & 63, w = t >> 6;
  const int wr = w >> 1, wc = w & 1;
  const int lr = lane & 15, lq = lane >> 4;
  const int sr = t >> 2, scg = t & 3;
  f32x4 acc[4][4];
  const f32x4 zero4 = {0.f,0.f,0.f,0.f};
  #pragma unroll
  for (int mt=0;mt<4;++mt)
    #pragma unroll
    for (int nt=0;nt<4;++nt) acc[mt][nt] = zero4;

  const unsigned short* ga0 = &A [(size_t)(m0 + sr     )*K + scg*8];
  const unsigned short* ga1 = &A [(size_t)(m0 + sr + 64)*K + scg*8];
  const unsigned short* gb0 = &Bt[(size_t)(n0 + sr     )*K + scg*8];
  const unsigned short* gb1 = &Bt[(size_t)(n0 + sr + 64)*K + scg*8];
  char* lA = (char*)As + w*1024;
  char* lB = (char*)Bs + w*1024;
  const int kiters = K >> 5;
  for (int kt = 0; kt < kiters; ++kt){
    __syncthreads();
    gload16(ga0 + kt*32, lA);
    gload16(ga1 + kt*32, lA + 4096);
    gload16(gb0 + kt*32, lB);
    gload16(gb1 + kt*32, lB + 4096);
    asm volatile("s_waitcnt vmcnt(0)" ::: "memory");
    __syncthreads();
    short8 af[4], bfr[4];
    #pragma unroll
    for (int mt=0; mt<4; ++mt)
      af[mt] = *reinterpret_cast<const short8*>(&As[(wr*64 + mt*16 + lr)*32 + lq*8]);
    #pragma unroll
    for (int nt=0; nt<4; ++nt)
      bfr[nt] = *reinterpret_cast<const short8*>(&Bs[(wc*64 + nt*16 + lr)*32 + lq*8]);
    #pragma unroll
    for (int mt=0; mt<4; ++mt)
      #pragma unroll
      for (int nt=0; nt<4; ++nt)
        acc[mt][nt] = __builtin_amdgcn_mfma_f32_16x16x32_bf16(af[mt], bfr[nt], acc[mt][nt], 0,0,0);
  }
  const bool isRZ = (n0 < 2048);
  #pragma unroll
  for (int mt=0;mt<4;++mt){
    #pragma unroll
    for (int nt=0;nt<4;++nt){
      int gn = n0 + wc*64 + nt*16 + lr;
      float bv = bias[gn];
      #pragma unroll
      for (int i=0;i<4;++i){
        int gm = m0 + wr*64 + mt*16 + lq*4 + i;
        float v = acc[mt][nt][i] + bv;
        if (isRZ) outRZ[(size_t)gm*2048 + gn] = f2bf(v);
        else      outC [(size_t)gm*1024 + (gn - 2048)] = v;
      }
    }
  }
}

// ---------------- persistent per-layer recurrent kernel ----------------
// 256 blocks x 512 threads. Block (g,c): batch rows [16g,16g+16) x cols
// [16c,16c+16). Cross-block state: plain-bf16 h and a via sc0sc1 ld/st.
// Hierarchical publish (r14). Epilogues split across 8 waves (r15).
// Output stores deferred one phase (this round).
__global__ __launch_bounds__(512) void k_gru_layer(
    const unsigned short* __restrict__ Wrzg,   // (2048,1024) bf16
    const unsigned short* __restrict__ Whhg,   // (1024,1024) bf16
    const unsigned short* __restrict__ XprojRZ,// (T,64,2048) bf16, biases folded
    const float* __restrict__ XprojC,          // (T,64,1024) fp32, biases folded
    unsigned short* hhi, unsigned short* abhi,
    unsigned short* __restrict__ h0seq,        // L0: bf16 sequence out (else null)
    float* __restrict__ outseq,                // L1: fp32 sequence out (else null)
    float* __restrict__ hn,                    // final h slot
    unsigned* bar)
{
  __shared__ __align__(16) unsigned short WrzS[32*1024]; // 64KB rows0-15=r,16-31=z
  __shared__ __align__(16) unsigned short WhhS[16*1024]; // 32KB
  __shared__ float hloc[16][17];                         // block's fp32 h tile
  __shared__ float zloc[16][17];                         // block's z tile
  __shared__ float part[8][64][9];                       // 8-wave K-combine

  const int bid = blockIdx.x;
  const int g = bid & 3;          // batch group (rows 16g..16g+16)
  const int c = bid >> 2;         // column group (cols 16c..16c+16)
  const int tid = threadIdx.x;
  const int lane = tid & 63, w = tid >> 6;
  const int lr = lane & 15, lq = lane >> 4;

  unsigned* c2  = bar + g*32;            // group counter
  unsigned* cen = bar + 1152 + g*8;      // census[8]
  unsigned xcc = 0, slot = 0, cx = 0, nx = 0;
  bool claim = false;
  unsigned* c1 = nullptr;
  if (tid == 0){
    asm volatile("s_getreg_b32 %0, hwreg(HW_REG_XCC_ID)" : "=s"(xcc));
    xcc &= 7;
    c1 = bar + 128 + (g*8 + (int)xcc)*32;
    slot = cadd(&cen[xcc]);
  }

  // ---- stage weights into LDS (once), XOR-swizzled ----
  #pragma unroll
  for (int j = 0; j < 8; ++j){
    int lin = (tid + j*512) * 8;
    int n = lin >> 10, k = lin & 1023;
    int gr = (n < 16) ? (16*c + n) : (1024 + 16*c + (n - 16));
    short8 v = *reinterpret_cast<const short8*>(&Wrzg[(size_t)gr*1024 + k]);
    *reinterpret_cast<short8*>(&WrzS[(n*1024 + k) ^ ((n&7)<<3)]) = v;
  }
  #pragma unroll
  for (int j = 0; j < 4; ++j){
    int lin = (tid + j*512) * 8;
    int n = lin >> 10, k = lin & 1023;
    short8 v = *reinterpret_cast<const short8*>(&Whhg[(size_t)(16*c + n)*1024 + k]);
    *reinterpret_cast<short8*>(&WhhS[(n*1024 + k) ^ ((n&7)<<3)]) = v;
  }
  // ---- zero local h tile and global h slice (ws is poisoned) ----
  for (int idx = tid; idx < 16*17; idx += 512) ((float*)hloc)[idx] = 0.f;
  if (tid < 128){
    int r = tid >> 3, cp = (tid & 7) * 2;
    cstore_u32(&hhi[(16*g + r)*1024 + 16*c + cp], 0u);
  }
  // ---- init rendezvous: publish h-zeros, finalize census ----
  __syncthreads();
  if (tid == 0){
    __builtin_amdgcn_fence(__ATOMIC_RELEASE, "agent");  // publish my stores
    cadd(c2);
    while (cld(c2) < GBLK) __builtin_amdgcn_s_sleep(1);
    cx = cld(&cen[xcc]);
    claim = (slot == 0);
    unsigned n = 0;
    for (int x = 0; x < 8; ++x) n += (cld(&cen[x]) != 0) ? 1u : 0u;
    nx = n;
  }
  __syncthreads();

  // hierarchical group barrier: per-XCD arrive -> claimant fence -> group ctr
  unsigned p = 0;   // phase counter (1..) — uniform across threads
  auto bar2 = [&](void){
    __syncthreads();
    ++p;
    if (tid == 0){
      cadd(c1);
      if (claim){
        const unsigned t1 = cx * p;
        while (cld(c1) < t1) {}
        __builtin_amdgcn_fence(__ATOMIC_RELEASE, "agent");   // one wbl2 per XCD
        cadd(c2);
      }
      const unsigned t2 = GBLK + nx * p;
      while (cld(c2) < t2) {}
    }
    __syncthreads();
  };

  const int kb = 128 * w;          // this wave's K-slice
  const int ei = w & 3;            // this wave's epilogue row-subindex
  const bool isR = (w < 4);        // r-waves vs z-waves
  const int erow = lq*4 + ei;      // epilogue row within the 16-row tile

  // prologue: prefetch step-0 xproj scalar (all waves)
  unsigned xv;
  PLOADU16(xv, &XprojRZ[(size_t)(16*g + erow)*2048 + (isR ? 0 : 1024) + 16*c + lr]);

  float xcv;
  unsigned d_h0 = 0;        // deferred h0seq word (isR, even lanes)
  u64 d_o64 = 0;            // deferred outseq / hn pair

  for (int t = 0; t < Tt; ++t){
    // ================= phase A: rz preact + gates =================
    {
      const unsigned short* hhp = hhi + (size_t)(16*g + lr)*1024 + kb + lq*8;
      u32x4 ahv[4];
      #pragma unroll
      for (int s = 0; s < 4; ++s){ CLOAD16(ahv[s], hhp, s) }
      f32x4 accr={0,0,0,0}, accz={0,0,0,0};
      #pragma unroll
      for (int k = 0; k < 4; ++k){
        VMWAIT(3 - k)
        short8 ah = __builtin_bit_cast(short8, ahv[k]);
        short8 br = *reinterpret_cast<const short8*>(
            &WrzS[(lr*1024 + kb + k*32 + lq*8) ^ ((lr&7)<<3)]);
        short8 bz = *reinterpret_cast<const short8*>(
            &WrzS[((16+lr)*1024 + kb + k*32 + lq*8) ^ ((lr&7)<<3)]);
        accr = __builtin_amdgcn_mfma_f32_16x16x32_bf16(ah, br, accr, 0,0,0);
        accz = __builtin_amdgcn_mfma_f32_16x16x32_bf16(ah, bz, accz, 0,0,0);
      }
      #pragma unroll
      for (int i = 0; i < 4; ++i){
        part[w][lane][i]   = accr[i];
        part[w][lane][4+i] = accz[i];
      }
      __syncthreads();
      if (isR){             // r-gate + a = h*r, row ei
        float s_ = 0.f;
        #pragma unroll
        for (int ww = 0; ww < 8; ++ww) s_ += part[ww][lane][ei];
        float pr = s_ + bf2f((unsigned short)xv);
        float rg = 1.f / (1.f + __expf(-pr));
        float av = hloc[erow][lr] * rg;
        unsigned short hi = f2bf(av);
        unsigned hi2 = (unsigned)__shfl_down((int)hi, 1) & 0xffffu;
        if (!(lane & 1))
          cstore_u32(&abhi[(16*g + erow)*1024 + 16*c + lr], (unsigned)hi | (hi2<<16));
        // hoist phase-B xc load: hides under the barrier
        PLOADF(xcv, &XprojC[(size_t)t*Bz*1024 + (16*g + erow)*1024 + 16*c + lr]);
      } else {              // z-gate, row ei
        float s_ = 0.f;
        #pragma unroll
        for (int ww = 0; ww < 8; ++ww) s_ += part[ww][lane][4+ei];
        float pz = s_ + bf2f((unsigned short)xv);
        zloc[erow][lr] = 1.f / (1.f + __expf(-pz));
      }
    }
    bar2();
    // ================= phase B: cand + state update =================
    {
      const unsigned short* ahp = abhi + (size_t)(16*g + lr)*1024 + kb + lq*8;
      u32x4 ahv[4];
      #pragma unroll
      for (int s = 0; s < 4; ++s){ CLOAD16(ahv[s], ahp, s) }
      // deferred output store for step t-1 (isR waves: exactly 1 VMEM op)
      const int td = t ? (t - 1) : 0;
      if (isR){
        if (!(lane & 1)){
          if (h0seq){
            ASTORE32(&h0seq[(size_t)td*(Bz*Hh) + (16*g + erow)*1024 + 16*c + lr], d_h0)
          } else {
            ASTORE64(&outseq[(size_t)td*(Bz*Hh) + (16*g + erow)*1024 + 16*c + lr], d_o64)
          }
        } else {
          // keep per-wave op count uniform is not needed across lanes (vmcnt is per-wave);
          // the masked store above already counts once for the whole wave.
        }
      }
      // prefetch next step's xproj scalar (all waves: 1 VMEM op)
      {
        const int tn = (t < Tt-1) ? (t + 1) : t;
        PLOADU16(xv, &XprojRZ[(size_t)tn*Bz*2048 + (16*g + erow)*2048 + (isR ? 0 : 1024) + 16*c + lr]);
      }
      f32x4 acc={0,0,0,0};
      if (isR){
        // ops outstanding: B0..B3, store, xv  -> ahv[k] ready at vmcnt(5-k)
        #pragma unroll
        for (int k = 0; k < 4; ++k){
          VMWAIT(5 - k)
          short8 ah = __builtin_bit_cast(short8, ahv[k]);
          short8 bb = *reinterpret_cast<const short8*>(
              &WhhS[(lr*1024 + kb + k*32 + lq*8) ^ ((lr&7)<<3)]);
          acc = __builtin_amdgcn_mfma_f32_16x16x32_bf16(ah, bb, acc, 0,0,0);
        }
      } else {
        // ops outstanding: B0..B3, xv -> ahv[k] ready at vmcnt(4-k)
        #pragma unroll
        for (int k = 0; k < 4; ++k){
          VMWAIT(4 - k)
          short8 ah = __builtin_bit_cast(short8, ahv[k]);
          short8 bb = *reinterpret_cast<const short8*>(
              &WhhS[(lr*1024 + kb + k*32 + lq*8) ^ ((lr&7)<<3)]);
          acc = __builtin_amdgcn_mfma_f32_16x16x32_bf16(ah, bb, acc, 0,0,0);
        }
      }
      #pragma unroll
      for (int i = 0; i < 4; ++i) part[w][lane][i] = acc[i];
      __syncthreads();
      if (isR){             // state update, row ei
        float s_ = 0.f;
        #pragma unroll
        for (int ww = 0; ww < 8; ++ww) s_ += part[ww][lane][ei];
        int grow = 16*g + erow, gcol = 16*c + lr;
        float pre = s_ + xcv;
        float cand = tanhf(pre);
        float zg = zloc[erow][lr];
        float h  = hloc[erow][lr];
        float hnew = zg*h + (1.f - zg)*cand;
        hloc[erow][lr] = hnew;
        unsigned short hi = f2bf(hnew);
        unsigned hi2 = (unsigned)__shfl_down((int)hi, 1) & 0xffffu;
        float hnew2 = __shfl_down(hnew, 1);
        if (!(lane & 1)){
          cstore_u32(&hhi[(size_t)grow*1024 + gcol], (unsigned)hi | (hi2<<16));
          // stash outputs for deferred store next phase
          d_h0 = (unsigned)hi | (hi2<<16);
          float2 pr2 = {hnew, hnew2};
          d_o64 = __builtin_bit_cast(u64, pr2);
        }
      }
    }
    bar2();
  }
  // flush the final step's deferred outputs + hn
  if (isR && !(lane & 1)){
    int grow = 16*g + erow, gcol = 16*c + lr;
    if (h0seq)  cstore_u32(&h0seq[(size_t)(Tt-1)*(Bz*Hh) + grow*1024 + gcol], d_h0);
    if (outseq) cstore_u64(&outseq[(size_t)(Tt-1)*(Bz*Hh) + grow*1024 + gcol], d_o64);
    cstore_u64(&hn[(size_t)grow*1024 + gcol], d_o64);
  }
}

// ---------------- host ----------------

extern "C" void kernel_launch(void* const* d_in, const int* in_sizes, int n_in,
                              void* d_out, int out_size, void* d_ws, size_t ws_size,
                              hipStream_t stream)
{
  (void)in_sizes; (void)n_in; (void)out_size; (void)ws_size;
  const float* X     = (const float*)d_in[0];
  const float* Wxrz0 = (const float*)d_in[1];
  const float* bxrz0 = (const float*)d_in[2];
  const float* Whrz0 = (const float*)d_in[3];
  const float* bhrz0 = (const float*)d_in[4];
  const float* Wxh0  = (const float*)d_in[5];
  const float* bxh0  = (const float*)d_in[6];
  const float* Whh0  = (const float*)d_in[7];
  const float* bhh0  = (const float*)d_in[8];
  const float* Wxrz1 = (const float*)d_in[9];
  const float* bxrz1 = (const float*)d_in[10];
  const float* Whrz1 = (const float*)d_in[11];
  const float* bhrz1 = (const float*)d_in[12];
  const float* Wxh1  = (const float*)d_in[13];
  const float* bxh1  = (const float*)d_in[14];
  const float* Whh1  = (const float*)d_in[15];
  const float* bhh1  = (const float*)d_in[16];

  char* p = (char*)d_ws;
  auto carve = [&](size_t bytes)->char*{
    char* r = p; p += (bytes + 255) & ~(size_t)255; return r;
  };
  unsigned short* Xbf    = (unsigned short*)carve((size_t)Mrows*512*2);
  unsigned short* W0t    = (unsigned short*)carve((size_t)3072*512*2);
  unsigned short* W1t    = (unsigned short*)carve((size_t)3072*1024*2);
  unsigned short* Whrz0t = (unsigned short*)carve((size_t)2048*1024*2);
  unsigned short* Whh0t  = (unsigned short*)carve((size_t)1024*1024*2);
  unsigned short* Whrz1t = (unsigned short*)carve((size_t)2048*1024*2);
  unsigned short* Whh1t  = (unsigned short*)carve((size_t)1024*1024*2);
  float* bias0 = (float*)carve(3072*4);
  float* bias1 = (float*)carve(3072*4);
  unsigned short* XprojRZ = (unsigned short*)carve((size_t)Mrows*2048*2);
  float*          XprojC  = (float*)carve((size_t)Mrows*1024*4);
  unsigned short* H0seq   = (unsigned short*)carve((size_t)Mrows*1024*2);
  unsigned short* hhi  = (unsigned short*)carve(Bz*Hh*2);
  unsigned short* abhi = (unsigned short*)carve(Bz*Hh*2);
  unsigned* bar = (unsigned*)carve(16384);  // L0 @ bar, L1 @ bar+2048 (u32)

  hipMemsetAsync(bar, 0, 16384, stream);

  k_cvt_bf16<<<2048,256,0,stream>>>(X, Xbf, Mrows*512/4);
  k_transpose_bf16<<<dim3(8,32), 256,0,stream>>>(Wxrz0, W0t, 512, 2048);
  k_transpose_bf16<<<dim3(8,16), 256,0,stream>>>(Wxh0,  W0t + (size_t)2048*512, 512, 1024);
  k_transpose_bf16<<<dim3(16,32),256,0,stream>>>(Whrz0, Whrz0t, 1024, 2048);
  k_transpose_bf16<<<dim3(16,16),256,0,stream>>>(Whh0,  Whh0t, 1024, 1024);
  k_transpose_bf16<<<dim3(16,32),256,0,stream>>>(Wxrz1, W1t, 1024, 2048);
  k_transpose_bf16<<<dim3(16,16),256,0,stream>>>(Wxh1,  W1t + (size_t)2048*1024, 1024, 1024);
  k_transpose_bf16<<<dim3(16,32),256,0,stream>>>(Whrz1, Whrz1t, 1024, 2048);
  k_transpose_bf16<<<dim3(16,16),256,0,stream>>>(Whh1,  Whh1t, 1024, 1024);
  k_bias_fold<<<12,256,0,stream>>>(bxrz0, bhrz0, bxh0, bhh0, bias0);
  k_bias_fold<<<12,256,0,stream>>>(bxrz1, bhrz1, bxh1, bhh1, bias1);

  float* out = (float*)d_out;
  float* hn0 = out + (size_t)Mrows*Hh;
  float* hn1 = hn0 + Bz*Hh;

  // ---- layer 0 ----
  k_xproj_gemm<<<dim3(24,256),256,0,stream>>>(Xbf, W0t, bias0, XprojRZ, XprojC, 512);
  k_gru_layer<<<256,512,0,stream>>>(Whrz0t, Whh0t, XprojRZ, XprojC,
                                    hhi, abhi,
                                    H0seq, nullptr, hn0, bar);
  // ---- layer 1 ----
  k_xproj_gemm<<<dim3(24,256),256,0,stream>>>(H0seq, W1t, bias1, XprojRZ, XprojC, 1024);
  k_gru_layer<<<256,512,0,stream>>>(Whrz1t, Whh1t, XprojRZ, XprojC,
                                    hhi, abhi,
                                    nullptr, out, hn1, bar + 2048);
}